// Round 14
// baseline (380.578 us; speedup 1.0000x reference)
//
#include <hip/hip_runtime.h>
#include <hip/hip_bf16.h>
#include <stdint.h>

#define S 4096
#define HID 1024
#define NH 16
#define DH 64

typedef __attribute__((ext_vector_type(8))) short short8;
typedef __attribute__((ext_vector_type(2))) float f32x2;
typedef __attribute__((ext_vector_type(4))) float f32x4;
typedef __attribute__((ext_vector_type(16))) float f32x16;
typedef __attribute__((ext_vector_type(4))) unsigned int u32x4;

#define VMCNT8 asm volatile("s_waitcnt vmcnt(8)" ::: "memory")
#define VMCNT4 asm volatile("s_waitcnt vmcnt(4)" ::: "memory")
#define VMCNT0 asm volatile("s_waitcnt vmcnt(0)" ::: "memory")
#define LGKM0  asm volatile("s_waitcnt lgkmcnt(0)" ::: "memory")

__device__ __forceinline__ unsigned short f2bf(float f) {
  unsigned int u = __builtin_bit_cast(unsigned int, f);
  u += 0x7FFF + ((u >> 16) & 1);   // round-to-nearest-even
  return (unsigned short)(u >> 16);
}
// pack two fp32 -> bf16x2 dword by truncation (1 v_perm_b32)
__device__ __forceinline__ unsigned int pktrunc(float lo, float hi) {
  return __builtin_amdgcn_perm(__builtin_bit_cast(unsigned int, hi),
                               __builtin_bit_cast(unsigned int, lo), 0x07060302u);
}
// async global->LDS, 16B per lane. LDS pointer MUST be wave-uniform;
// HW writes lane i at ldsbase + i*16B (m104/m108 semantics).
__device__ __forceinline__ void gload16(const unsigned short* g, unsigned short* l) {
  __builtin_amdgcn_global_load_lds((const __attribute__((address_space(1))) unsigned int*)g,
                                   (__attribute__((address_space(3))) unsigned int*)l, 16, 0, 0);
}

// ---------------------------------------------------------------- cast fp32 -> bf16
// Right-sized grid (1024,8): y<4 -> x slices (4096 chunks), y>=4 -> one
// weight each (1024 chunks, exact). Block (0,4) zeroes vsum.
__global__ __launch_bounds__(256) void cast_kernel(
    const float* __restrict__ x,  const float* __restrict__ wq,
    const float* __restrict__ wk, const float* __restrict__ wv,
    const float* __restrict__ wo,
    unsigned short* __restrict__ xb,  unsigned short* __restrict__ wqb,
    unsigned short* __restrict__ wkb, unsigned short* __restrict__ wvb,
    unsigned short* __restrict__ wob, float* __restrict__ vsum)
{
  const int y = blockIdx.y, bx = blockIdx.x;
  const float* src; unsigned short* dst; int cx;
  if (y < 4)       { src = x;  dst = xb;  cx = y * 1024 + bx; }
  else if (y == 4) { src = wq; dst = wqb; cx = bx; }
  else if (y == 5) { src = wk; dst = wkb; cx = bx; }
  else if (y == 6) { src = wv; dst = wvb; cx = bx; }
  else             { src = wo; dst = wob; cx = bx; }
  if (y == 4 && bx == 0) {
    f32x4 z = {0.f, 0.f, 0.f, 0.f};
    reinterpret_cast<f32x4*>(vsum)[threadIdx.x] = z;   // 256*4 = 1024 floats
  }
  int i = (cx * 256 + threadIdx.x) * 4;
  float4 v = *reinterpret_cast<const float4*>(src + i);
  ushort4 o;
  o.x = f2bf(v.x); o.y = f2bf(v.y); o.z = f2bf(v.z); o.w = f2bf(v.w);
  *reinterpret_cast<ushort4*>(dst + i) = o;
}

// ---------------------------------------------------------------- 128x128 NT GEMM core (m97-style)
__device__ __forceinline__ void gemm128(
    const unsigned short* __restrict__ A, const unsigned short* __restrict__ W,
    unsigned short* As, unsigned short* Bs, f32x4 acc[4][4], int row0, int col0)
{
  const int tid = threadIdx.x;
  const int wave = tid >> 6, lane = tid & 63, quad = lane >> 4, l16 = lane & 15;
  const int wr = (wave >> 1) * 64, wc = (wave & 1) * 64;
  const int srow = lane >> 2, sseg = lane & 3;
  const f32x4 z = {0.f, 0.f, 0.f, 0.f};
  #pragma unroll
  for (int i = 0; i < 4; i++)
    #pragma unroll
    for (int j = 0; j < 4; j++) acc[i][j] = z;

  for (int k0 = 0; k0 < HID; k0 += 32) {
    __syncthreads();
    #pragma unroll
    for (int c = 0; c < 2; c++) {
      const int rbase = c * 64 + wave * 16;
      gload16(A + (size_t)(row0 + rbase + srow) * HID + k0 + sseg * 8, As + rbase * 32);
      gload16(W + (size_t)(col0 + rbase + srow) * HID + k0 + sseg * 8, Bs + rbase * 32);
    }
    __syncthreads();

    short8 af[4], bfr[4];
    #pragma unroll
    for (int i = 0; i < 4; i++)
      af[i] = *reinterpret_cast<const short8*>(As + (wr + i * 16 + l16) * 32 + quad * 8);
    #pragma unroll
    for (int j = 0; j < 4; j++)
      bfr[j] = *reinterpret_cast<const short8*>(Bs + (wc + j * 16 + l16) * 32 + quad * 8);
    #pragma unroll
    for (int i = 0; i < 4; i++)
      #pragma unroll
      for (int j = 0; j < 4; j++)
        acc[i][j] = __builtin_amdgcn_mfma_f32_16x16x32_bf16(af[i], bfr[j], acc[i][j], 0, 0, 0);
  }
}

// QKV projections. Q -> [H][S][64] prescaled by log2e/8.
// K -> K2 frag-packed (K=16 A-op): K2[(((h*128+g)*4+c)*64 + lane)*8 + j]
// V -> Vb frag-packed (K=16 B-op with keys bitswap23-relabeled).
// Epilogues route through a 32KB LDS image laid out exactly as the
// destination global bytes, then one barrier + coalesced dwordx4 copy-out.
__global__ __launch_bounds__(256) void qkv_gemm_kernel(
    const unsigned short* __restrict__ X,
    const unsigned short* __restrict__ Wq, const unsigned short* __restrict__ Wk,
    const unsigned short* __restrict__ Wv,
    const float* __restrict__ bq, const float* __restrict__ bk, const float* __restrict__ bv,
    unsigned short* __restrict__ Qo, unsigned short* __restrict__ K2o, unsigned short* __restrict__ Vbo,
    float* __restrict__ Vsum)
{
  __shared__ unsigned short As[128 * 32];
  __shared__ unsigned short Bs[128 * 32];
  __shared__ unsigned short Ep[16384];            // 32KB epilogue image
  const int zsel = blockIdx.z;
  const unsigned short* W = (zsel == 0) ? Wq : (zsel == 1) ? Wk : Wv;
  const float* bias        = (zsel == 0) ? bq : (zsel == 1) ? bk : bv;
  const int row0 = blockIdx.x * 128, col0 = blockIdx.y * 128;
  f32x4 acc[4][4];
  gemm128(X, W, As, Bs, acc, row0, col0);

  const int tid = threadIdx.x;
  const int wave = tid >> 6, lane = tid & 63, quad = lane >> 4, l16 = lane & 15;
  const int wr = (wave >> 1) * 64, wc = (wave & 1) * 64;
  const int h0 = col0 >> 6, g0 = row0 >> 5;

  if (zsel == 0) {
    const float osc = 0.18033688011112042f;   // log2(e)/8
    #pragma unroll
    for (int j = 0; j < 4; j++) {
      int rc = wc + j * 16 + l16;             // 0..127 within tile
      float bb = bias[col0 + rc];
      int hh = rc >> 6, d = rc & 63;
      #pragma unroll
      for (int i = 0; i < 4; i++)
        #pragma unroll
        for (int rr = 0; rr < 4; rr++) {
          int srel = wr + i * 16 + quad * 4 + rr;
          Ep[hh * 8192 + srel * 64 + d] = f2bf((acc[i][j][rr] + bb) * osc);
        }
    }
  } else if (zsel == 1) {
    #pragma unroll
    for (int j = 0; j < 4; j++) {
      int rc = wc + j * 16 + l16;
      float bb = bias[col0 + rc];
      int hh = rc >> 6, dh = rc & 63;
      int c = dh >> 4, hfk = (dh >> 3) & 1, j8 = dh & 7;
      #pragma unroll
      for (int i = 0; i < 4; i++)
        #pragma unroll
        for (int rr = 0; rr < 4; rr++) {
          int srel = wr + i * 16 + quad * 4 + rr;
          int gl = srel >> 5, l32k = srel & 31;
          Ep[(hh * 4 + gl) * 2048 + (c * 64 + hfk * 32 + l32k) * 8 + j8] =
              f2bf(acc[i][j][rr] + bb);
        }
    }
  } else {
    // m = key&15 = quad*4+rr -> hf_v = quad&1, j = (quad>>1)*4 + rr, grp = i&1
    #pragma unroll
    for (int j = 0; j < 4; j++) {
      int rc = wc + j * 16 + l16;
      float bb = bias[col0 + rc];
      int hh = rc >> 6, dh = rc & 63;
      int ng = dh >> 5, l32v = dh & 31;
      int hf_v = quad & 1, jj0 = (quad >> 1) * 4;
      float colsum = 0.f;
      #pragma unroll
      for (int i = 0; i < 4; i++) {
        int gt4 = (wr + i * 16) >> 5;
        int grp = i & 1;
        float v0 = acc[i][j][0] + bb, v1 = acc[i][j][1] + bb;
        float v2 = acc[i][j][2] + bb, v3 = acc[i][j][3] + bb;
        colsum += (v0 + v1) + (v2 + v3);
        ushort4 pv;
        pv.x = f2bf(v0); pv.y = f2bf(v1); pv.z = f2bf(v2); pv.w = f2bf(v3);
        *reinterpret_cast<ushort4*>(
            Ep + (((hh * 4 + gt4) * 2 + grp) * 2 + ng) * 512 + (hf_v * 32 + l32v) * 8 + jj0) = pv;
      }
      // reduce 16-row partial across the 4 quads (same col), one atomic/col
      colsum += __shfl_xor(colsum, 16);
      colsum += __shfl_xor(colsum, 32);
      if (quad == 0) atomicAdd(&Vsum[col0 + rc], colsum);
    }
  }
  __syncthreads();

  // coalesced copy-out: 32KB in 8 rounds of 256 thr x 16B
  #pragma unroll
  for (int it = 0; it < 8; it++) {
    int flat = it * 2048 + tid * 8;           // short index, 16B-aligned
    u32x4 v = *reinterpret_cast<const u32x4*>(Ep + flat);
    if (zsel == 0) {
      int hh = flat >> 13;
      size_t goff = ((size_t)(h0 + hh) * S + row0) * 64 + (flat & 8191);
      *reinterpret_cast<u32x4*>(Qo + goff) = v;
    } else if (zsel == 1) {
      int sp = flat >> 11, hh = sp >> 2, g4 = sp & 3;
      size_t goff = (size_t)((h0 + hh) * 128 + g0 + g4) * 2048 + (flat & 2047);
      *reinterpret_cast<u32x4*>(K2o + goff) = v;
    } else {
      int sp = flat >> 9;
      int ng = sp & 1, grp = (sp >> 1) & 1, gt4 = (sp >> 2) & 3, hh = sp >> 4;
      size_t goff = (size_t)((((h0 + hh) * 128 + g0 + gt4) * 2 + grp) * 2 + ng) * 512 + (flat & 511);
      *reinterpret_cast<u32x4*>(Vbo + goff) = v;
    }
  }
}

// out = A @ W^T + bias_eff  (stores 64B-coalesced: 16 lanes x 4B)
__global__ __launch_bounds__(256) void out_gemm_kernel(
    const unsigned short* __restrict__ A, const unsigned short* __restrict__ W,
    const float* __restrict__ be, float* __restrict__ dst)
{
  __shared__ unsigned short As[128 * 32];
  __shared__ unsigned short Bs[128 * 32];
  const int row0 = blockIdx.x * 128, col0 = blockIdx.y * 128;
  f32x4 acc[4][4];
  gemm128(A, W, As, Bs, acc, row0, col0);

  const int tid = threadIdx.x;
  const int wave = tid >> 6, lane = tid & 63, quad = lane >> 4, l16 = lane & 15;
  const int wr = (wave >> 1) * 64, wc = (wave & 1) * 64;
  #pragma unroll
  for (int j = 0; j < 4; j++) {
    int n = col0 + wc + j * 16 + l16;
    float bb = be[n];
    #pragma unroll
    for (int i = 0; i < 4; i++)
      #pragma unroll
      for (int rr = 0; rr < 4; rr++) {
        int s = row0 + wr + i * 16 + quad * 4 + rr;
        dst[(size_t)s * HID + n] = acc[i][j][rr] + bb;
      }
  }
}

// ---------------------------------------------------------------- attention v19
// = v12 pipeline at 3 waves/SIMD. v13/v14 tested occupancy only WITH a
// serializing single-buffer loop (vmcnt(0)+lgkm(0) drain per tile — T4
// violation); this keeps v12's counted-vmcnt schedule intact and halves LDS
// by moving V out of LDS entirely: V is consumed lane-linear (no layout
// transform) and L2-resident -> register double-buffer, 1-tile-ahead
// prefetch, landing guaranteed by the existing vmcnt(8). K keeps the LDS
// 2-ahead path. LDS 64KB -> 33KB; launch_bounds(256,3) (cap ~170 — NOT 4,
// v13's spill trap) -> 3 blocks/CU = 3 waves/SIMD (+50% issue capacity).
// Epilogue: v14's 2-round reduction in the dead 32KB K-tile LDS.
struct AttnState {
  short8 qf[2][4];
  f32x16 Oa[2][2];
  f32x16 zacc;
  f32x2  zp[2];
};

__device__ __forceinline__ void loadK(
    const unsigned short* kb, short8 (&kf)[4])
{
  #pragma unroll
  for (int c = 0; c < 4; c++)
    kf[c] = *reinterpret_cast<const short8*>(kb + c * 512);
}

// V global->reg, 4x dwordx4 per lane (coalesced; same frag layout as LDS path)
__device__ __forceinline__ void loadV(
    const unsigned short* gVt, short8 (&vf)[4])
{
  #pragma unroll
  for (int w = 0; w < 4; w++)
    vf[w] = *reinterpret_cast<const short8*>(gVt + w * 512);
}

__device__ __forceinline__ void attn_compute(
    const short8 (&kf)[4], const short8 (&vfr)[4], AttnState& st)
{
  #pragma unroll
  for (int qh = 0; qh < 2; qh++) {
    // S^T tile: 32 keys x 32 q (C: col=q=l32, row=key=(reg&3)+4hf+8(reg>>2))
    f32x16 acc = __builtin_amdgcn_mfma_f32_32x32x16_bf16(kf[0], st.qf[qh][0], st.zacc, 0, 0, 0);
    #pragma unroll
    for (int c = 1; c < 4; c++)
      acc = __builtin_amdgcn_mfma_f32_32x32x16_bf16(kf[c], st.qf[qh][c], acc, 0, 0, 0);

    // exp + pack: reg-octet [0..7] / [8..15] become K=16 A-operands directly
    unsigned int D[8];
    #pragma unroll
    for (int m = 0; m < 8; m++) {
      float t0 = __builtin_amdgcn_exp2f(acc[2 * m]);
      float t1 = __builtin_amdgcn_exp2f(acc[2 * m + 1]);
      f32x2 t = {t0, t1};
      st.zp[qh] += t;                      // v_pk_add_f32
      D[m] = pktrunc(t0, t1);
    }
    u32x4 dv0 = {D[0], D[1], D[2], D[3]};
    u32x4 dv1 = {D[4], D[5], D[6], D[7]};
    short8 A0 = __builtin_bit_cast(short8, dv0);
    short8 A1 = __builtin_bit_cast(short8, dv1);

    st.Oa[qh][0] = __builtin_amdgcn_mfma_f32_32x32x16_bf16(A0, vfr[0], st.Oa[qh][0], 0, 0, 0);
    st.Oa[qh][1] = __builtin_amdgcn_mfma_f32_32x32x16_bf16(A0, vfr[1], st.Oa[qh][1], 0, 0, 0);
    st.Oa[qh][0] = __builtin_amdgcn_mfma_f32_32x32x16_bf16(A1, vfr[2], st.Oa[qh][0], 0, 0, 0);
    st.Oa[qh][1] = __builtin_amdgcn_mfma_f32_32x32x16_bf16(A1, vfr[3], st.Oa[qh][1], 0, 0, 0);
  }
}

__device__ __forceinline__ void stageK(
    const unsigned short* gK, unsigned short* lK)
{
  #pragma unroll
  for (int i = 0; i < 4; i++) gload16(gK + i * 512, lK + i * 512);
}

__global__ __launch_bounds__(256, 3) void attn_kernel(
    const unsigned short* __restrict__ Q, const unsigned short* __restrict__ K2,
    const unsigned short* __restrict__ Vb, unsigned short* __restrict__ OUT,
    const float* __restrict__ Vsum, const float* __restrict__ wo,
    const float* __restrict__ bo, float* __restrict__ be)
{
  // ---- biasfold rider blocks (y == 16): be[n] = bo[n] + (Vsum.wo[n,:])/4097
  if (blockIdx.y == 16) {
    const int base = blockIdx.x * 16 + (threadIdx.x >> 6) * 4;
    const int l = threadIdx.x & 63;
    #pragma unroll
    for (int c = 0; c < 4; c++) {
      const int n = base + c;
      float acc = 0.f;
      #pragma unroll
      for (int i = 0; i < 16; i++)
        acc += Vsum[l + 64 * i] * wo[(size_t)n * HID + l + 64 * i];
      #pragma unroll
      for (int off = 32; off >= 1; off >>= 1) acc += __shfl_xor(acc, off);
      if (l == 0) be[n] = bo[n] + acc * (1.f / 4097.f);
    }
    return;
  }

  __shared__ unsigned short T[4][2][2048];   // [wave][dbuf][2048] K tiles = 32KB
  __shared__ float Zl[256];                   // [wave][64 q]
  float* Ored = reinterpret_cast<float*>(&T[0][0][0]);   // [2][64][64] after loop

  // XCD-aware remap: XCD x owns heads {2x,2x+1}: K2+Vb working set 2MB (L2-fit).
  const int lin = blockIdx.y * 64 + blockIdx.x;
  const int xcd = lin & 7, idx = lin >> 3;
  const int h = xcd * 2 + (idx >> 6);
  const int q0 = (idx & 63) * 64;

  const int tid = threadIdx.x;
  const int wave = tid >> 6, lane = tid & 63, hf = lane >> 5, l32 = lane & 31;

  AttnState st;
  // Q B-frags for BOTH q-halves (loop-invariant): B[k=c*16+hf*8+j][q=l32]
  #pragma unroll
  for (int qh = 0; qh < 2; qh++) {
    const unsigned short* qrow = Q + (size_t)(h * S + q0 + qh * 32 + l32) * DH;
    #pragma unroll
    for (int c = 0; c < 4; c++)
      st.qf[qh][c] = *reinterpret_cast<const short8*>(qrow + c * 16 + hf * 8);
  }
  #pragma unroll
  for (int r = 0; r < 16; r++) {
    st.zacc[r] = 0.f;
    st.Oa[0][0][r] = 0.f; st.Oa[0][1][r] = 0.f;
    st.Oa[1][0][r] = 0.f; st.Oa[1][1][r] = 0.f;
  }
  st.zp[0] = (f32x2){0.f, 0.f};
  st.zp[1] = (f32x2){0.f, 0.f};

  const unsigned short* Kb  = K2 + (size_t)h * 128 * 2048;
  const unsigned short* Vbb = Vb + (size_t)h * 128 * 2048;

  // wave handles tiles g = wave + 4*i, i = 0..31 (each tile = 4KB K + 4KB V)
  const unsigned short* gKb = Kb  + (size_t)wave * 2048 + (size_t)lane * 8;
  const unsigned short* gVb = Vbb + (size_t)wave * 2048 + (size_t)lane * 8;
  unsigned short* lK0 = &T[wave][0][0];   // wave-uniform LDS dests
  unsigned short* lK1 = &T[wave][1][0];
  const unsigned short* kb0 = &T[wave][0][0] + lane * 8;
  const unsigned short* kb1 = &T[wave][1][0] + lane * 8;
  const ptrdiff_t STR = 4 * 2048;   // 4 tiles ahead (wave stride)

  short8 kA[4], vA[4], kB[4], vB[4];

  // prologue: K0->buf0, V0->vA, K1->buf1 (12 vmem ops); wait K0+V0 (8 oldest)
  stageK(gKb, lK0);                 // 4 ops
  loadV(gVb, vA);                   // 4 ops
  stageK(gKb + STR, lK1);           // 4 ops (K1 may stay in flight)
  VMCNT4;                           // K0 in LDS, V0 in regs
  loadK(kb0, kA);                   // ds_read K0 (pending)
  LGKM0;                            // kA valid; buf0 free for re-stage

  const unsigned short* gK2 = gKb + 2 * STR;   // next K tile to stage (t+2)
  const unsigned short* gV1 = gVb + STR;       // next V tile to load  (t+1)

  // 15 pairs: computes tiles 0..29, stages K 2..31, loads V 1..30
  for (int p = 0; p < 15; p++) {
    // even t=2p: stage K(t+2)->buf0, load V(t+1)->vB, read K(t+1)->kB, compute A(t)
    stageK(gK2, lK0); gK2 += STR;   // 4 ops
    loadV(gV1, vB);   gV1 += STR;   // 4 ops
    VMCNT8;                          // K(t+1) in LDS, V(t) in vA landed
    loadK(kb1, kB);                  // pending
    attn_compute(kA, vA, st);        // reg-only
    LGKM0;                           // kB valid; buf1 free
    // odd t=2p+1: stage K(t+3)->buf1, load V(t+2)->vA, read K(t+2)->kA, compute B(t+1)
    stageK(gK2, lK1); gK2 += STR;   // 4 ops
    loadV(gV1, vA);   gV1 += STR;   // 4 ops
    VMCNT8;                          // K(t+2) in LDS, V(t+1) in vB landed
    loadK(kb0, kA);                  // pending
    attn_compute(kB, vB, st);        // reg-only
    LGKM0;                           // kA valid; buf0 free
  }
  // tail: computed 0..29; kA=K(30), vA=V(30) in flight; K(31) staged to buf1
  loadV(gV1, vB);                    // V(31) -> vB (4 ops)
  VMCNT4;                            // K(31) in LDS + V(30) in vA landed
  loadK(kb1, kB);                    // K(31) (pending)
  attn_compute(kA, vA, st);          // tile 30
  LGKM0;
  VMCNT0;                            // V(31) landed
  attn_compute(kB, vB, st);          // tile 31

  // ---- epilogue: 2-round cross-wave reduction in the dead 32KB K-tile LDS ----
  __syncthreads();   // all waves done with T
  {
    float za = st.zp[0][0] + st.zp[0][1];
    float zb = st.zp[1][0] + st.zp[1][1];
    za += __shfl_xor(za, 32);
    zb += __shfl_xor(zb, 32);
    if (hf == 0) {
      Zl[wave * 64 + l32]      = za;
      Zl[wave * 64 + 32 + l32] = zb;
    }
    if (wave >= 2) {
      float* Ow = Ored + (wave - 2) * 4096;   // [64 q][64 d]
      #pragma unroll
      for (int qh = 0; qh < 2; qh++)
        #pragma unroll
        for (int ng = 0; ng < 2; ng++)
          #pragma unroll
          for (int r = 0; r < 16; r++) {
            const int row = (r & 3) + 8 * (r >> 2) + 4 * hf;
            Ow[(qh * 32 + row) * 64 + ng * 32 + l32] = st.Oa[qh][ng][r];
          }
    }
  }
  __syncthreads();
  if (wave < 2) {
    float* Ow = Ored + wave * 4096;
    #pragma unroll
    for (int qh = 0; qh < 2; qh++)
      #pragma unroll
      for (int ng = 0; ng < 2; ng++)
        #pragma unroll
        for (int r = 0; r < 16; r++) {
          const int row = (r & 3) + 8 * (r >> 2) + 4 * hf;
          const int ix = (qh * 32 + row) * 64 + ng * 32 + l32;
          Ow[ix] += st.Oa[qh][ng][r];
        }
  }
  __syncthreads();
  {
    const int q = tid >> 2, d0 = (tid & 3) * 16;
    const float* O0 = Ored + q * 64 + d0;
    const float* O1 = Ored + 4096 + q * 64 + d0;
    f32x4 s0 = *reinterpret_cast<const f32x4*>(O0)      + *reinterpret_cast<const f32x4*>(O1);
    f32x4 s1 = *reinterpret_cast<const f32x4*>(O0 + 4)  + *reinterpret_cast<const f32x4*>(O1 + 4);
    f32x4 s2 = *reinterpret_cast<const f32x4*>(O0 + 8)  + *reinterpret_cast<const f32x4*>(O1 + 8);
    f32x4 s3 = *reinterpret_cast<const f32x4*>(O0 + 12) + *reinterpret_cast<const f32x4*>(O1 + 12);
    const float zt = Zl[q] + Zl[64 + q] + Zl[128 + q] + Zl[192 + q];
    const float rz = 1.f / (zt * 4097.f);
    unsigned short* op = OUT + (size_t)(q0 + q) * HID + h * DH + d0;
    ushort4 u;
    u.x = f2bf(s0[0] * rz); u.y = f2bf(s0[1] * rz);
    u.z = f2bf(s0[2] * rz); u.w = f2bf(s0[3] * rz);
    *reinterpret_cast<ushort4*>(op) = u;
    u.x = f2bf(s1[0] * rz); u.y = f2bf(s1[1] * rz);
    u.z = f2bf(s1[2] * rz); u.w = f2bf(s1[3] * rz);
    *reinterpret_cast<ushort4*>(op + 4) = u;
    u.x = f2bf(s2[0] * rz); u.y = f2bf(s2[1] * rz);
    u.z = f2bf(s2[2] * rz); u.w = f2bf(s2[3] * rz);
    *reinterpret_cast<ushort4*>(op + 8) = u;
    u.x = f2bf(s3[0] * rz); u.y = f2bf(s3[1] * rz);
    u.z = f2bf(s3[2] * rz); u.w = f2bf(s3[3] * rz);
    *reinterpret_cast<ushort4*>(op + 12) = u;
  }
}

// ----------------------------------------------------------------
extern "C" void kernel_launch(void* const* d_in, const int* in_sizes, int n_in,
                              void* d_out, int out_size, void* d_ws, size_t ws_size,
                              hipStream_t stream) {
  const float* x  = (const float*)d_in[0];
  const float* wq = (const float*)d_in[1];
  const float* bq = (const float*)d_in[2];
  const float* wk = (const float*)d_in[3];
  const float* bk = (const float*)d_in[4];
  const float* wv = (const float*)d_in[5];
  const float* bv = (const float*)d_in[6];
  const float* wo = (const float*)d_in[7];
  const float* bo = (const float*)d_in[8];
  float* out = (float*)d_out;

  char* ws = (char*)d_ws;
  unsigned short* xb  = (unsigned short*)(ws);                 // 8 MB (reused for attn out)
  unsigned short* wqb = (unsigned short*)(ws + (8u  << 20));
  unsigned short* wkb = (unsigned short*)(ws + (10u << 20));
  unsigned short* wvb = (unsigned short*)(ws + (12u << 20));
  unsigned short* wob = (unsigned short*)(ws + (14u << 20));
  unsigned short* qw  = (unsigned short*)(ws + (16u << 20));   // [H][S][64] prescaled
  unsigned short* k2  = (unsigned short*)(ws + (24u << 20));   // frag-packed K (K=16 A-op)
  unsigned short* vb  = (unsigned short*)(ws + (32u << 20));   // frag-packed V (K=16 B-op, relabeled)
  float* vsum         = (float*)(ws + (40u << 20));            // [1024]
  float* be           = (float*)(ws + (40u << 20) + 65536);    // [1024]
  unsigned short* aw  = xb;

  cast_kernel<<<dim3(1024, 8), 256, 0, stream>>>(x, wq, wk, wv, wo, xb, wqb, wkb, wvb, wob, vsum);
  qkv_gemm_kernel<<<dim3(32, 8, 3), 256, 0, stream>>>(xb, wqb, wkb, wvb, bq, bk, bv, qw, k2, vb, vsum);
  attn_kernel<<<dim3(64, 17), 256, 0, stream>>>(qw, k2, vb, aw, vsum, wo, bo, be);
  out_gemm_kernel<<<dim3(32, 8, 1), 256, 0, stream>>>(aw, wob, be, out);
}

// Round 15
// 237.744 us; speedup vs baseline: 1.6008x; 1.6008x over previous
//
#include <hip/hip_runtime.h>
#include <hip/hip_bf16.h>
#include <stdint.h>

#define S 4096
#define HID 1024
#define NH 16
#define DH 64

typedef __attribute__((ext_vector_type(8))) short short8;
typedef __attribute__((ext_vector_type(2))) float f32x2;
typedef __attribute__((ext_vector_type(4))) float f32x4;
typedef __attribute__((ext_vector_type(16))) float f32x16;
typedef __attribute__((ext_vector_type(4))) unsigned int u32x4;

#define VMCNT8 asm volatile("s_waitcnt vmcnt(8)" ::: "memory")
#define VMCNT0 asm volatile("s_waitcnt vmcnt(0)" ::: "memory")
#define LGKM0  asm volatile("s_waitcnt lgkmcnt(0)" ::: "memory")

__device__ __forceinline__ unsigned short f2bf(float f) {
  unsigned int u = __builtin_bit_cast(unsigned int, f);
  u += 0x7FFF + ((u >> 16) & 1);   // round-to-nearest-even
  return (unsigned short)(u >> 16);
}
// pack two fp32 -> bf16x2 dword by truncation (1 v_perm_b32)
__device__ __forceinline__ unsigned int pktrunc(float lo, float hi) {
  return __builtin_amdgcn_perm(__builtin_bit_cast(unsigned int, hi),
                               __builtin_bit_cast(unsigned int, lo), 0x07060302u);
}
// async global->LDS, 16B per lane. LDS pointer MUST be wave-uniform;
// HW writes lane i at ldsbase + i*16B (m104/m108 semantics).
__device__ __forceinline__ void gload16(const unsigned short* g, unsigned short* l) {
  __builtin_amdgcn_global_load_lds((const __attribute__((address_space(1))) unsigned int*)g,
                                   (__attribute__((address_space(3))) unsigned int*)l, 16, 0, 0);
}

// ---------------------------------------------------------------- cast fp32 -> bf16
// Right-sized grid (1024,8): y<4 -> x slices (4096 chunks), y>=4 -> one
// weight each (1024 chunks, exact). Block (0,4) zeroes vsum.
__global__ __launch_bounds__(256) void cast_kernel(
    const float* __restrict__ x,  const float* __restrict__ wq,
    const float* __restrict__ wk, const float* __restrict__ wv,
    const float* __restrict__ wo,
    unsigned short* __restrict__ xb,  unsigned short* __restrict__ wqb,
    unsigned short* __restrict__ wkb, unsigned short* __restrict__ wvb,
    unsigned short* __restrict__ wob, float* __restrict__ vsum)
{
  const int y = blockIdx.y, bx = blockIdx.x;
  const float* src; unsigned short* dst; int cx;
  if (y < 4)       { src = x;  dst = xb;  cx = y * 1024 + bx; }
  else if (y == 4) { src = wq; dst = wqb; cx = bx; }
  else if (y == 5) { src = wk; dst = wkb; cx = bx; }
  else if (y == 6) { src = wv; dst = wvb; cx = bx; }
  else             { src = wo; dst = wob; cx = bx; }
  if (y == 4 && bx == 0) {
    f32x4 z = {0.f, 0.f, 0.f, 0.f};
    reinterpret_cast<f32x4*>(vsum)[threadIdx.x] = z;   // 256*4 = 1024 floats
  }
  int i = (cx * 256 + threadIdx.x) * 4;
  float4 v = *reinterpret_cast<const float4*>(src + i);
  ushort4 o;
  o.x = f2bf(v.x); o.y = f2bf(v.y); o.z = f2bf(v.z); o.w = f2bf(v.w);
  *reinterpret_cast<ushort4*>(dst + i) = o;
}

// ---------------------------------------------------------------- 128x128 NT GEMM core (m97-style)
__device__ __forceinline__ void gemm128(
    const unsigned short* __restrict__ A, const unsigned short* __restrict__ W,
    unsigned short* As, unsigned short* Bs, f32x4 acc[4][4], int row0, int col0)
{
  const int tid = threadIdx.x;
  const int wave = tid >> 6, lane = tid & 63, quad = lane >> 4, l16 = lane & 15;
  const int wr = (wave >> 1) * 64, wc = (wave & 1) * 64;
  const int srow = lane >> 2, sseg = lane & 3;
  const f32x4 z = {0.f, 0.f, 0.f, 0.f};
  #pragma unroll
  for (int i = 0; i < 4; i++)
    #pragma unroll
    for (int j = 0; j < 4; j++) acc[i][j] = z;

  for (int k0 = 0; k0 < HID; k0 += 32) {
    __syncthreads();
    #pragma unroll
    for (int c = 0; c < 2; c++) {
      const int rbase = c * 64 + wave * 16;
      gload16(A + (size_t)(row0 + rbase + srow) * HID + k0 + sseg * 8, As + rbase * 32);
      gload16(W + (size_t)(col0 + rbase + srow) * HID + k0 + sseg * 8, Bs + rbase * 32);
    }
    __syncthreads();

    short8 af[4], bfr[4];
    #pragma unroll
    for (int i = 0; i < 4; i++)
      af[i] = *reinterpret_cast<const short8*>(As + (wr + i * 16 + l16) * 32 + quad * 8);
    #pragma unroll
    for (int j = 0; j < 4; j++)
      bfr[j] = *reinterpret_cast<const short8*>(Bs + (wc + j * 16 + l16) * 32 + quad * 8);
    #pragma unroll
    for (int i = 0; i < 4; i++)
      #pragma unroll
      for (int j = 0; j < 4; j++)
        acc[i][j] = __builtin_amdgcn_mfma_f32_16x16x32_bf16(af[i], bfr[j], acc[i][j], 0, 0, 0);
  }
}

// QKV projections. Q -> [H][S][64] prescaled by log2e/8.
// K -> K2 frag-packed (K=16 A-op): K2[(((h*128+g)*4+c)*64 + lane)*8 + j]
// V -> Vb frag-packed (K=16 B-op with keys bitswap23-relabeled).
// Epilogues route through a 32KB LDS image laid out exactly as the
// destination global bytes, then one barrier + coalesced dwordx4 copy-out.
__global__ __launch_bounds__(256) void qkv_gemm_kernel(
    const unsigned short* __restrict__ X,
    const unsigned short* __restrict__ Wq, const unsigned short* __restrict__ Wk,
    const unsigned short* __restrict__ Wv,
    const float* __restrict__ bq, const float* __restrict__ bk, const float* __restrict__ bv,
    unsigned short* __restrict__ Qo, unsigned short* __restrict__ K2o, unsigned short* __restrict__ Vbo,
    float* __restrict__ Vsum)
{
  __shared__ unsigned short As[128 * 32];
  __shared__ unsigned short Bs[128 * 32];
  __shared__ unsigned short Ep[16384];            // 32KB epilogue image
  const int zsel = blockIdx.z;
  const unsigned short* W = (zsel == 0) ? Wq : (zsel == 1) ? Wk : Wv;
  const float* bias        = (zsel == 0) ? bq : (zsel == 1) ? bk : bv;
  const int row0 = blockIdx.x * 128, col0 = blockIdx.y * 128;
  f32x4 acc[4][4];
  gemm128(X, W, As, Bs, acc, row0, col0);

  const int tid = threadIdx.x;
  const int wave = tid >> 6, lane = tid & 63, quad = lane >> 4, l16 = lane & 15;
  const int wr = (wave >> 1) * 64, wc = (wave & 1) * 64;
  const int h0 = col0 >> 6, g0 = row0 >> 5;

  if (zsel == 0) {
    const float osc = 0.18033688011112042f;   // log2(e)/8
    #pragma unroll
    for (int j = 0; j < 4; j++) {
      int rc = wc + j * 16 + l16;             // 0..127 within tile
      float bb = bias[col0 + rc];
      int hh = rc >> 6, d = rc & 63;
      #pragma unroll
      for (int i = 0; i < 4; i++)
        #pragma unroll
        for (int rr = 0; rr < 4; rr++) {
          int srel = wr + i * 16 + quad * 4 + rr;
          Ep[hh * 8192 + srel * 64 + d] = f2bf((acc[i][j][rr] + bb) * osc);
        }
    }
  } else if (zsel == 1) {
    #pragma unroll
    for (int j = 0; j < 4; j++) {
      int rc = wc + j * 16 + l16;
      float bb = bias[col0 + rc];
      int hh = rc >> 6, dh = rc & 63;
      int c = dh >> 4, hfk = (dh >> 3) & 1, j8 = dh & 7;
      #pragma unroll
      for (int i = 0; i < 4; i++)
        #pragma unroll
        for (int rr = 0; rr < 4; rr++) {
          int srel = wr + i * 16 + quad * 4 + rr;
          int gl = srel >> 5, l32k = srel & 31;
          Ep[(hh * 4 + gl) * 2048 + (c * 64 + hfk * 32 + l32k) * 8 + j8] =
              f2bf(acc[i][j][rr] + bb);
        }
    }
  } else {
    // m = key&15 = quad*4+rr -> hf_v = quad&1, j = (quad>>1)*4 + rr, grp = i&1
    #pragma unroll
    for (int j = 0; j < 4; j++) {
      int rc = wc + j * 16 + l16;
      float bb = bias[col0 + rc];
      int hh = rc >> 6, dh = rc & 63;
      int ng = dh >> 5, l32v = dh & 31;
      int hf_v = quad & 1, jj0 = (quad >> 1) * 4;
      float colsum = 0.f;
      #pragma unroll
      for (int i = 0; i < 4; i++) {
        int gt4 = (wr + i * 16) >> 5;
        int grp = i & 1;
        float v0 = acc[i][j][0] + bb, v1 = acc[i][j][1] + bb;
        float v2 = acc[i][j][2] + bb, v3 = acc[i][j][3] + bb;
        colsum += (v0 + v1) + (v2 + v3);
        ushort4 pv;
        pv.x = f2bf(v0); pv.y = f2bf(v1); pv.z = f2bf(v2); pv.w = f2bf(v3);
        *reinterpret_cast<ushort4*>(
            Ep + (((hh * 4 + gt4) * 2 + grp) * 2 + ng) * 512 + (hf_v * 32 + l32v) * 8 + jj0) = pv;
      }
      // reduce 16-row partial across the 4 quads (same col), one atomic/col
      colsum += __shfl_xor(colsum, 16);
      colsum += __shfl_xor(colsum, 32);
      if (quad == 0) atomicAdd(&Vsum[col0 + rc], colsum);
    }
  }
  __syncthreads();

  // coalesced copy-out: 32KB in 8 rounds of 256 thr x 16B
  #pragma unroll
  for (int it = 0; it < 8; it++) {
    int flat = it * 2048 + tid * 8;           // short index, 16B-aligned
    u32x4 v = *reinterpret_cast<const u32x4*>(Ep + flat);
    if (zsel == 0) {
      int hh = flat >> 13;
      size_t goff = ((size_t)(h0 + hh) * S + row0) * 64 + (flat & 8191);
      *reinterpret_cast<u32x4*>(Qo + goff) = v;
    } else if (zsel == 1) {
      int sp = flat >> 11, hh = sp >> 2, g4 = sp & 3;
      size_t goff = (size_t)((h0 + hh) * 128 + g0 + g4) * 2048 + (flat & 2047);
      *reinterpret_cast<u32x4*>(K2o + goff) = v;
    } else {
      int sp = flat >> 9;
      int ng = sp & 1, grp = (sp >> 1) & 1, gt4 = (sp >> 2) & 3, hh = sp >> 4;
      size_t goff = (size_t)((((h0 + hh) * 128 + g0 + gt4) * 2 + grp) * 2 + ng) * 512 + (flat & 511);
      *reinterpret_cast<u32x4*>(Vbo + goff) = v;
    }
  }
}

// out = A @ W^T + bias_eff  (stores 64B-coalesced: 16 lanes x 4B)
__global__ __launch_bounds__(256) void out_gemm_kernel(
    const unsigned short* __restrict__ A, const unsigned short* __restrict__ W,
    const float* __restrict__ be, float* __restrict__ dst)
{
  __shared__ unsigned short As[128 * 32];
  __shared__ unsigned short Bs[128 * 32];
  const int row0 = blockIdx.x * 128, col0 = blockIdx.y * 128;
  f32x4 acc[4][4];
  gemm128(A, W, As, Bs, acc, row0, col0);

  const int tid = threadIdx.x;
  const int wave = tid >> 6, lane = tid & 63, quad = lane >> 4, l16 = lane & 15;
  const int wr = (wave >> 1) * 64, wc = (wave & 1) * 64;
  #pragma unroll
  for (int j = 0; j < 4; j++) {
    int n = col0 + wc + j * 16 + l16;
    float bb = be[n];
    #pragma unroll
    for (int i = 0; i < 4; i++)
      #pragma unroll
      for (int rr = 0; rr < 4; rr++) {
        int s = row0 + wr + i * 16 + quad * 4 + rr;
        dst[(size_t)s * HID + n] = acc[i][j][rr] + bb;
      }
  }
}

// ---------------------------------------------------------------- attention v20 (= v18, session best)
// Collapsed double softmax (w = 1+p): out = (Vsum + softmax1(S)V)/4097.
// v12 pipeline at 2 waves/SIMD — the empirical optimum of this decomposition:
//   v13/v14 (single-buffer + occupancy): slower (per-tile full drain serializes)
//   v17 (setprio): slower (scheduler fence; VGPR 128->108, MfmaUtil -5)
//   v19 (V-in-regs + 3 waves): spill catastrophe (WRITE 8->358MB)
// 3-stage 2-deep register pipeline per tile t:
//   stage t+2 -> vmcnt(8) -> issue ds_read t+1 -> compute t (reg-only) -> lgkm(0)
// + biasfold rider as blockIdx.y==16.
struct AttnState {
  short8 qf[2][4];
  f32x16 Oa[2][2];
  f32x16 zacc;
  f32x2  zp[2];
};

__device__ __forceinline__ void loadregs(
    const unsigned short* kb, const unsigned short* vb,
    short8 (&kf)[4], short8 (&vf)[4])
{
  #pragma unroll
  for (int c = 0; c < 4; c++)
    kf[c] = *reinterpret_cast<const short8*>(kb + c * 512);
  #pragma unroll
  for (int w = 0; w < 4; w++)
    vf[w] = *reinterpret_cast<const short8*>(vb + w * 512);
}

__device__ __forceinline__ void attn_compute(
    const short8 (&kf)[4], const short8 (&vfr)[4], AttnState& st)
{
  #pragma unroll
  for (int qh = 0; qh < 2; qh++) {
    // S^T tile: 32 keys x 32 q (C: col=q=l32, row=key=(reg&3)+4hf+8(reg>>2))
    f32x16 acc = __builtin_amdgcn_mfma_f32_32x32x16_bf16(kf[0], st.qf[qh][0], st.zacc, 0, 0, 0);
    #pragma unroll
    for (int c = 1; c < 4; c++)
      acc = __builtin_amdgcn_mfma_f32_32x32x16_bf16(kf[c], st.qf[qh][c], acc, 0, 0, 0);

    // exp + pack: reg-octet [0..7] / [8..15] become K=16 A-operands directly
    unsigned int D[8];
    #pragma unroll
    for (int m = 0; m < 8; m++) {
      float t0 = __builtin_amdgcn_exp2f(acc[2 * m]);
      float t1 = __builtin_amdgcn_exp2f(acc[2 * m + 1]);
      f32x2 t = {t0, t1};
      st.zp[qh] += t;                      // v_pk_add_f32
      D[m] = pktrunc(t0, t1);
    }
    u32x4 dv0 = {D[0], D[1], D[2], D[3]};
    u32x4 dv1 = {D[4], D[5], D[6], D[7]};
    short8 A0 = __builtin_bit_cast(short8, dv0);
    short8 A1 = __builtin_bit_cast(short8, dv1);

    st.Oa[qh][0] = __builtin_amdgcn_mfma_f32_32x32x16_bf16(A0, vfr[0], st.Oa[qh][0], 0, 0, 0);
    st.Oa[qh][1] = __builtin_amdgcn_mfma_f32_32x32x16_bf16(A0, vfr[1], st.Oa[qh][1], 0, 0, 0);
    st.Oa[qh][0] = __builtin_amdgcn_mfma_f32_32x32x16_bf16(A1, vfr[2], st.Oa[qh][0], 0, 0, 0);
    st.Oa[qh][1] = __builtin_amdgcn_mfma_f32_32x32x16_bf16(A1, vfr[3], st.Oa[qh][1], 0, 0, 0);
  }
}

__device__ __forceinline__ void stage_tile(
    const unsigned short* gK, const unsigned short* gV,
    unsigned short* lK, unsigned short* lV)
{
  #pragma unroll
  for (int i = 0; i < 4; i++) gload16(gK + i * 512, lK + i * 512);
  #pragma unroll
  for (int i = 0; i < 4; i++) gload16(gV + i * 512, lV + i * 512);
}

__global__ __launch_bounds__(256, 2) void attn_kernel(
    const unsigned short* __restrict__ Q, const unsigned short* __restrict__ K2,
    const unsigned short* __restrict__ Vb, unsigned short* __restrict__ OUT,
    const float* __restrict__ Vsum, const float* __restrict__ wo,
    const float* __restrict__ bo, float* __restrict__ be)
{
  // ---- biasfold rider blocks (y == 16): be[n] = bo[n] + (Vsum.wo[n,:])/4097
  if (blockIdx.y == 16) {
    const int base = blockIdx.x * 16 + (threadIdx.x >> 6) * 4;
    const int l = threadIdx.x & 63;
    #pragma unroll
    for (int c = 0; c < 4; c++) {
      const int n = base + c;
      float acc = 0.f;
      #pragma unroll
      for (int i = 0; i < 16; i++)
        acc += Vsum[l + 64 * i] * wo[(size_t)n * HID + l + 64 * i];
      #pragma unroll
      for (int off = 32; off >= 1; off >>= 1) acc += __shfl_xor(acc, off);
      if (l == 0) be[n] = bo[n] + acc * (1.f / 4097.f);
    }
    return;
  }

  __shared__ unsigned short T[4][2][2][2048];   // [wave][dbuf][K|V][2048] = 64KB
  __shared__ float Zl[256];                      // [wave][64 q]
  float* Ored = reinterpret_cast<float*>(&T[0][0][0][0]);   // [4][64][64] after loop

  // XCD-aware remap: XCD x owns heads {2x,2x+1}: K2+Vb working set 2MB (L2-fit).
  const int lin = blockIdx.y * 64 + blockIdx.x;
  const int xcd = lin & 7, idx = lin >> 3;
  const int h = xcd * 2 + (idx >> 6);
  const int q0 = (idx & 63) * 64;

  const int tid = threadIdx.x;
  const int wave = tid >> 6, lane = tid & 63, hf = lane >> 5, l32 = lane & 31;

  AttnState st;
  // Q B-frags for BOTH q-halves (loop-invariant): B[k=c*16+hf*8+j][q=l32]
  #pragma unroll
  for (int qh = 0; qh < 2; qh++) {
    const unsigned short* qrow = Q + (size_t)(h * S + q0 + qh * 32 + l32) * DH;
    #pragma unroll
    for (int c = 0; c < 4; c++)
      st.qf[qh][c] = *reinterpret_cast<const short8*>(qrow + c * 16 + hf * 8);
  }
  #pragma unroll
  for (int r = 0; r < 16; r++) {
    st.zacc[r] = 0.f;
    st.Oa[0][0][r] = 0.f; st.Oa[0][1][r] = 0.f;
    st.Oa[1][0][r] = 0.f; st.Oa[1][1][r] = 0.f;
  }
  st.zp[0] = (f32x2){0.f, 0.f};
  st.zp[1] = (f32x2){0.f, 0.f};

  const unsigned short* Kb  = K2 + (size_t)h * 128 * 2048;
  const unsigned short* Vbb = Vb + (size_t)h * 128 * 2048;

  // wave handles tiles g = wave + 4*i, i = 0..31 (each tile = 4KB K + 4KB V)
  const unsigned short* gK = Kb  + (size_t)wave * 2048 + (size_t)lane * 8;
  const unsigned short* gV = Vbb + (size_t)wave * 2048 + (size_t)lane * 8;
  unsigned short* lK0 = &T[wave][0][0][0];   // wave-uniform LDS dests
  unsigned short* lV0 = &T[wave][0][1][0];
  unsigned short* lK1 = &T[wave][1][0][0];
  unsigned short* lV1 = &T[wave][1][1][0];
  const unsigned short* kb0 = &T[wave][0][0][0] + lane * 8;
  const unsigned short* vb0 = &T[wave][0][1][0] + lane * 8;
  const unsigned short* kb1 = &T[wave][1][0][0] + lane * 8;
  const unsigned short* vb1 = &T[wave][1][1][0] + lane * 8;
  const ptrdiff_t STR = 4 * 2048;   // 4 tiles ahead (wave stride)

  short8 kA[4], vA[4], kB[4], vB[4];

  // prologue: tile0 -> buf0 -> regsA; tile1 -> buf1 (in flight)
  stage_tile(gK, gV, lK0, lV0); gK += STR; gV += STR;   // out 8
  VMCNT0;
  loadregs(kb0, vb0, kA, vA);                           // ds_reads pending
  stage_tile(gK, gV, lK1, lV1); gK += STR; gV += STR;   // out 8 (buf1 untouched by reads)
  LGKM0;                                                // regsA valid; buf0 free for re-stage

  // 15 pairs: computes tiles 0..29, stages 2..31
  for (int p = 0; p < 15; p++) {
    // even t=2p: stage t+2->buf0, read t+1->B, compute A(t)
    stage_tile(gK, gV, lK0, lV0); gK += STR; gV += STR;   // out 16
    VMCNT8;                                               // t+1 landed
    loadregs(kb1, vb1, kB, vB);                           // pending
    attn_compute(kA, vA, st);                             // reg-only
    LGKM0;                                                // B valid; buf1 free
    // odd t=2p+1: stage t+3->buf1, read t+2->A, compute B(t+1)
    stage_tile(gK, gV, lK1, lV1); gK += STR; gV += STR;   // out 16
    VMCNT8;                                               // t+2 landed
    loadregs(kb0, vb0, kA, vA);                           // pending
    attn_compute(kB, vB, st);                             // reg-only
    LGKM0;                                                // A valid; buf0 free
  }
  // after loop: computed 0..29, A = tile30, outstanding = tile31 (8)
  VMCNT0;
  loadregs(kb1, vb1, kB, vB);    // tile31
  attn_compute(kA, vA, st);      // tile30
  attn_compute(kB, vB, st);      // tile31 (compiler inserts lgkm before use)

  // ---- epilogue: cross-wave reduction through the dead tile LDS ----
  __syncthreads();   // everyone done streaming; T reusable as Ored
  {
    float za = st.zp[0][0] + st.zp[0][1];
    float zb = st.zp[1][0] + st.zp[1][1];
    za += __shfl_xor(za, 32);
    zb += __shfl_xor(zb, 32);
    if (hf == 0) {
      Zl[wave * 64 + l32]      = za;
      Zl[wave * 64 + 32 + l32] = zb;
    }
    float* Ow = Ored + wave * 4096;   // [64 q][64 d]
    #pragma unroll
    for (int qh = 0; qh < 2; qh++)
      #pragma unroll
      for (int ng = 0; ng < 2; ng++)
        #pragma unroll
        for (int r = 0; r < 16; r++) {
          const int row = (r & 3) + 8 * (r >> 2) + 4 * hf;
          Ow[(qh * 32 + row) * 64 + ng * 32 + l32] = st.Oa[qh][ng][r];
        }
  }
  __syncthreads();
  {
    const int q = tid >> 2, d0 = (tid & 3) * 16;
    const float* O0 = Ored + q * 64 + d0;
    f32x4 s0 = *reinterpret_cast<const f32x4*>(O0);
    f32x4 s1 = *reinterpret_cast<const f32x4*>(O0 + 4);
    f32x4 s2 = *reinterpret_cast<const f32x4*>(O0 + 8);
    f32x4 s3 = *reinterpret_cast<const f32x4*>(O0 + 12);
    #pragma unroll
    for (int w = 1; w < 4; w++) {
      const float* Ow = Ored + w * 4096 + q * 64 + d0;
      s0 += *reinterpret_cast<const f32x4*>(Ow);
      s1 += *reinterpret_cast<const f32x4*>(Ow + 4);
      s2 += *reinterpret_cast<const f32x4*>(Ow + 8);
      s3 += *reinterpret_cast<const f32x4*>(Ow + 12);
    }
    const float zt = Zl[q] + Zl[64 + q] + Zl[128 + q] + Zl[192 + q];
    const float rz = 1.f / (zt * 4097.f);
    unsigned short* op = OUT + (size_t)(q0 + q) * HID + h * DH + d0;
    ushort4 u;
    u.x = f2bf(s0[0] * rz); u.y = f2bf(s0[1] * rz);
    u.z = f2bf(s0[2] * rz); u.w = f2bf(s0[3] * rz);
    *reinterpret_cast<ushort4*>(op) = u;
    u.x = f2bf(s1[0] * rz); u.y = f2bf(s1[1] * rz);
    u.z = f2bf(s1[2] * rz); u.w = f2bf(s1[3] * rz);
    *reinterpret_cast<ushort4*>(op + 4) = u;
    u.x = f2bf(s2[0] * rz); u.y = f2bf(s2[1] * rz);
    u.z = f2bf(s2[2] * rz); u.w = f2bf(s2[3] * rz);
    *reinterpret_cast<ushort4*>(op + 8) = u;
    u.x = f2bf(s3[0] * rz); u.y = f2bf(s3[1] * rz);
    u.z = f2bf(s3[2] * rz); u.w = f2bf(s3[3] * rz);
    *reinterpret_cast<ushort4*>(op + 12) = u;
  }
}

// ----------------------------------------------------------------
extern "C" void kernel_launch(void* const* d_in, const int* in_sizes, int n_in,
                              void* d_out, int out_size, void* d_ws, size_t ws_size,
                              hipStream_t stream) {
  const float* x  = (const float*)d_in[0];
  const float* wq = (const float*)d_in[1];
  const float* bq = (const float*)d_in[2];
  const float* wk = (const float*)d_in[3];
  const float* bk = (const float*)d_in[4];
  const float* wv = (const float*)d_in[5];
  const float* bv = (const float*)d_in[6];
  const float* wo = (const float*)d_in[7];
  const float* bo = (const float*)d_in[8];
  float* out = (float*)d_out;

  char* ws = (char*)d_ws;
  unsigned short* xb  = (unsigned short*)(ws);                 // 8 MB (reused for attn out)
  unsigned short* wqb = (unsigned short*)(ws + (8u  << 20));
  unsigned short* wkb = (unsigned short*)(ws + (10u << 20));
  unsigned short* wvb = (unsigned short*)(ws + (12u << 20));
  unsigned short* wob = (unsigned short*)(ws + (14u << 20));
  unsigned short* qw  = (unsigned short*)(ws + (16u << 20));   // [H][S][64] prescaled
  unsigned short* k2  = (unsigned short*)(ws + (24u << 20));   // frag-packed K (K=16 A-op)
  unsigned short* vb  = (unsigned short*)(ws + (32u << 20));   // frag-packed V (K=16 B-op, relabeled)
  float* vsum         = (float*)(ws + (40u << 20));            // [1024]
  float* be           = (float*)(ws + (40u << 20) + 65536);    // [1024]
  unsigned short* aw  = xb;

  cast_kernel<<<dim3(1024, 8), 256, 0, stream>>>(x, wq, wk, wv, wo, xb, wqb, wkb, wvb, wob, vsum);
  qkv_gemm_kernel<<<dim3(32, 8, 3), 256, 0, stream>>>(xb, wqb, wkb, wvb, bq, bk, bv, qw, k2, vb, vsum);
  attn_kernel<<<dim3(64, 17), 256, 0, stream>>>(qw, k2, vb, aw, vsum, wo, bo, be);
  out_gemm_kernel<<<dim3(32, 8, 1), 256, 0, stream>>>(aw, wob, be, out);
}

// Round 16
// 229.283 us; speedup vs baseline: 1.6599x; 1.0369x over previous
//
#include <hip/hip_runtime.h>
#include <hip/hip_bf16.h>
#include <stdint.h>

#define S 4096
#define HID 1024
#define NH 16
#define DH 64

typedef __attribute__((ext_vector_type(8))) short short8;
typedef __attribute__((ext_vector_type(2))) float f32x2;
typedef __attribute__((ext_vector_type(4))) float f32x4;
typedef __attribute__((ext_vector_type(16))) float f32x16;
typedef __attribute__((ext_vector_type(4))) unsigned int u32x4;

#define VMCNT8 asm volatile("s_waitcnt vmcnt(8)" ::: "memory")
#define VMCNT0 asm volatile("s_waitcnt vmcnt(0)" ::: "memory")
#define LGKM0  asm volatile("s_waitcnt lgkmcnt(0)" ::: "memory")

__device__ __forceinline__ unsigned short f2bf(float f) {
  unsigned int u = __builtin_bit_cast(unsigned int, f);
  u += 0x7FFF + ((u >> 16) & 1);   // round-to-nearest-even
  return (unsigned short)(u >> 16);
}
// pack two fp32 -> bf16x2 dword by truncation (1 v_perm_b32)
__device__ __forceinline__ unsigned int pktrunc(float lo, float hi) {
  return __builtin_amdgcn_perm(__builtin_bit_cast(unsigned int, hi),
                               __builtin_bit_cast(unsigned int, lo), 0x07060302u);
}
// async global->LDS, 16B per lane. LDS pointer MUST be wave-uniform;
// HW writes lane i at ldsbase + i*16B (m104/m108 semantics).
__device__ __forceinline__ void gload16(const unsigned short* g, unsigned short* l) {
  __builtin_amdgcn_global_load_lds((const __attribute__((address_space(1))) unsigned int*)g,
                                   (__attribute__((address_space(3))) unsigned int*)l, 16, 0, 0);
}

// ---------------------------------------------------------------- cast fp32 -> bf16
// Right-sized grid (1024,8): y<4 -> x slices (4096 chunks), y>=4 -> one
// weight each (1024 chunks, exact). Block (0,4) zeroes vsum.
__global__ __launch_bounds__(256) void cast_kernel(
    const float* __restrict__ x,  const float* __restrict__ wq,
    const float* __restrict__ wk, const float* __restrict__ wv,
    const float* __restrict__ wo,
    unsigned short* __restrict__ xb,  unsigned short* __restrict__ wqb,
    unsigned short* __restrict__ wkb, unsigned short* __restrict__ wvb,
    unsigned short* __restrict__ wob, float* __restrict__ vsum)
{
  const int y = blockIdx.y, bx = blockIdx.x;
  const float* src; unsigned short* dst; int cx;
  if (y < 4)       { src = x;  dst = xb;  cx = y * 1024 + bx; }
  else if (y == 4) { src = wq; dst = wqb; cx = bx; }
  else if (y == 5) { src = wk; dst = wkb; cx = bx; }
  else if (y == 6) { src = wv; dst = wvb; cx = bx; }
  else             { src = wo; dst = wob; cx = bx; }
  if (y == 4 && bx == 0) {
    f32x4 z = {0.f, 0.f, 0.f, 0.f};
    reinterpret_cast<f32x4*>(vsum)[threadIdx.x] = z;   // 256*4 = 1024 floats
  }
  int i = (cx * 256 + threadIdx.x) * 4;
  float4 v = *reinterpret_cast<const float4*>(src + i);
  ushort4 o;
  o.x = f2bf(v.x); o.y = f2bf(v.y); o.z = f2bf(v.z); o.w = f2bf(v.w);
  *reinterpret_cast<ushort4*>(dst + i) = o;
}

// ---------------------------------------------------------------- 128x128 NT GEMM core (m97-style)
__device__ __forceinline__ void gemm128(
    const unsigned short* __restrict__ A, const unsigned short* __restrict__ W,
    unsigned short* As, unsigned short* Bs, f32x4 acc[4][4], int row0, int col0)
{
  const int tid = threadIdx.x;
  const int wave = tid >> 6, lane = tid & 63, quad = lane >> 4, l16 = lane & 15;
  const int wr = (wave >> 1) * 64, wc = (wave & 1) * 64;
  const int srow = lane >> 2, sseg = lane & 3;
  const f32x4 z = {0.f, 0.f, 0.f, 0.f};
  #pragma unroll
  for (int i = 0; i < 4; i++)
    #pragma unroll
    for (int j = 0; j < 4; j++) acc[i][j] = z;

  for (int k0 = 0; k0 < HID; k0 += 32) {
    __syncthreads();
    #pragma unroll
    for (int c = 0; c < 2; c++) {
      const int rbase = c * 64 + wave * 16;
      gload16(A + (size_t)(row0 + rbase + srow) * HID + k0 + sseg * 8, As + rbase * 32);
      gload16(W + (size_t)(col0 + rbase + srow) * HID + k0 + sseg * 8, Bs + rbase * 32);
    }
    __syncthreads();

    short8 af[4], bfr[4];
    #pragma unroll
    for (int i = 0; i < 4; i++)
      af[i] = *reinterpret_cast<const short8*>(As + (wr + i * 16 + l16) * 32 + quad * 8);
    #pragma unroll
    for (int j = 0; j < 4; j++)
      bfr[j] = *reinterpret_cast<const short8*>(Bs + (wc + j * 16 + l16) * 32 + quad * 8);
    #pragma unroll
    for (int i = 0; i < 4; i++)
      #pragma unroll
      for (int j = 0; j < 4; j++)
        acc[i][j] = __builtin_amdgcn_mfma_f32_16x16x32_bf16(af[i], bfr[j], acc[i][j], 0, 0, 0);
  }
}

// QKV projections. Q -> [H][S][64] prescaled by log2e/8.
// K -> K2 frag-packed (K=16 A-op): K2[(((h*128+g)*4+c)*64 + lane)*8 + j]
// V -> Vb frag-packed (K=16 B-op with keys bitswap23-relabeled).
// Epilogues route through a 32KB LDS image laid out exactly as the
// destination global bytes, then one barrier + coalesced dwordx4 copy-out.
__global__ __launch_bounds__(256) void qkv_gemm_kernel(
    const unsigned short* __restrict__ X,
    const unsigned short* __restrict__ Wq, const unsigned short* __restrict__ Wk,
    const unsigned short* __restrict__ Wv,
    const float* __restrict__ bq, const float* __restrict__ bk, const float* __restrict__ bv,
    unsigned short* __restrict__ Qo, unsigned short* __restrict__ K2o, unsigned short* __restrict__ Vbo,
    float* __restrict__ Vsum)
{
  __shared__ unsigned short As[128 * 32];
  __shared__ unsigned short Bs[128 * 32];
  __shared__ unsigned short Ep[16384];            // 32KB epilogue image
  const int zsel = blockIdx.z;
  const unsigned short* W = (zsel == 0) ? Wq : (zsel == 1) ? Wk : Wv;
  const float* bias        = (zsel == 0) ? bq : (zsel == 1) ? bk : bv;
  const int row0 = blockIdx.x * 128, col0 = blockIdx.y * 128;
  f32x4 acc[4][4];
  gemm128(X, W, As, Bs, acc, row0, col0);

  const int tid = threadIdx.x;
  const int wave = tid >> 6, lane = tid & 63, quad = lane >> 4, l16 = lane & 15;
  const int wr = (wave >> 1) * 64, wc = (wave & 1) * 64;
  const int h0 = col0 >> 6, g0 = row0 >> 5;

  if (zsel == 0) {
    const float osc = 0.18033688011112042f;   // log2(e)/8
    #pragma unroll
    for (int j = 0; j < 4; j++) {
      int rc = wc + j * 16 + l16;             // 0..127 within tile
      float bb = bias[col0 + rc];
      int hh = rc >> 6, d = rc & 63;
      #pragma unroll
      for (int i = 0; i < 4; i++)
        #pragma unroll
        for (int rr = 0; rr < 4; rr++) {
          int srel = wr + i * 16 + quad * 4 + rr;
          Ep[hh * 8192 + srel * 64 + d] = f2bf((acc[i][j][rr] + bb) * osc);
        }
    }
  } else if (zsel == 1) {
    #pragma unroll
    for (int j = 0; j < 4; j++) {
      int rc = wc + j * 16 + l16;
      float bb = bias[col0 + rc];
      int hh = rc >> 6, dh = rc & 63;
      int c = dh >> 4, hfk = (dh >> 3) & 1, j8 = dh & 7;
      #pragma unroll
      for (int i = 0; i < 4; i++)
        #pragma unroll
        for (int rr = 0; rr < 4; rr++) {
          int srel = wr + i * 16 + quad * 4 + rr;
          int gl = srel >> 5, l32k = srel & 31;
          Ep[(hh * 4 + gl) * 2048 + (c * 64 + hfk * 32 + l32k) * 8 + j8] =
              f2bf(acc[i][j][rr] + bb);
        }
    }
  } else {
    // m = key&15 = quad*4+rr -> hf_v = quad&1, j = (quad>>1)*4 + rr, grp = i&1
    #pragma unroll
    for (int j = 0; j < 4; j++) {
      int rc = wc + j * 16 + l16;
      float bb = bias[col0 + rc];
      int hh = rc >> 6, dh = rc & 63;
      int ng = dh >> 5, l32v = dh & 31;
      int hf_v = quad & 1, jj0 = (quad >> 1) * 4;
      float colsum = 0.f;
      #pragma unroll
      for (int i = 0; i < 4; i++) {
        int gt4 = (wr + i * 16) >> 5;
        int grp = i & 1;
        float v0 = acc[i][j][0] + bb, v1 = acc[i][j][1] + bb;
        float v2 = acc[i][j][2] + bb, v3 = acc[i][j][3] + bb;
        colsum += (v0 + v1) + (v2 + v3);
        ushort4 pv;
        pv.x = f2bf(v0); pv.y = f2bf(v1); pv.z = f2bf(v2); pv.w = f2bf(v3);
        *reinterpret_cast<ushort4*>(
            Ep + (((hh * 4 + gt4) * 2 + grp) * 2 + ng) * 512 + (hf_v * 32 + l32v) * 8 + jj0) = pv;
      }
      // reduce 16-row partial across the 4 quads (same col), one atomic/col
      colsum += __shfl_xor(colsum, 16);
      colsum += __shfl_xor(colsum, 32);
      if (quad == 0) atomicAdd(&Vsum[col0 + rc], colsum);
    }
  }
  __syncthreads();

  // coalesced copy-out: 32KB in 8 rounds of 256 thr x 16B
  #pragma unroll
  for (int it = 0; it < 8; it++) {
    int flat = it * 2048 + tid * 8;           // short index, 16B-aligned
    u32x4 v = *reinterpret_cast<const u32x4*>(Ep + flat);
    if (zsel == 0) {
      int hh = flat >> 13;
      size_t goff = ((size_t)(h0 + hh) * S + row0) * 64 + (flat & 8191);
      *reinterpret_cast<u32x4*>(Qo + goff) = v;
    } else if (zsel == 1) {
      int sp = flat >> 11, hh = sp >> 2, g4 = sp & 3;
      size_t goff = (size_t)((h0 + hh) * 128 + g0 + g4) * 2048 + (flat & 2047);
      *reinterpret_cast<u32x4*>(K2o + goff) = v;
    } else {
      int sp = flat >> 9;
      int ng = sp & 1, grp = (sp >> 1) & 1, gt4 = (sp >> 2) & 3, hh = sp >> 4;
      size_t goff = (size_t)((((h0 + hh) * 128 + g0 + gt4) * 2 + grp) * 2 + ng) * 512 + (flat & 511);
      *reinterpret_cast<u32x4*>(Vbo + goff) = v;
    }
  }
}

// out = A @ W^T + bias_eff
// v21: 128x64 tiles (grid 32x16 = 512 blocks = 2 blocks/CU; was 128x128 =
// 256 blocks = 1 block/CU, leaving the per-k-step vmcnt(0)+barrier drain
// fully exposed — no co-resident block to overlap [m114 mechanism]).
// Each wave owns 32 rows x 64 cols: acc[2][4], 8 MFMA/k-step.
// Staging/wave/k-step: 2x A-chunk + 1x B-chunk gload16. LDS 12KB.
__global__ __launch_bounds__(256) void out_gemm_kernel(
    const unsigned short* __restrict__ A, const unsigned short* __restrict__ W,
    const float* __restrict__ be, float* __restrict__ dst)
{
  __shared__ unsigned short As[128 * 32];   // 8KB
  __shared__ unsigned short Bs[64 * 32];    // 4KB
  const int row0 = blockIdx.x * 128, col0 = blockIdx.y * 64;
  const int tid = threadIdx.x;
  const int wave = tid >> 6, lane = tid & 63, quad = lane >> 4, l16 = lane & 15;
  const int srow = lane >> 2, sseg = lane & 3;
  f32x4 acc[2][4];
  const f32x4 z = {0.f, 0.f, 0.f, 0.f};
  #pragma unroll
  for (int i = 0; i < 2; i++)
    #pragma unroll
    for (int j = 0; j < 4; j++) acc[i][j] = z;

  for (int k0 = 0; k0 < HID; k0 += 32) {
    __syncthreads();
    #pragma unroll
    for (int c = 0; c < 2; c++) {
      const int rbase = c * 64 + wave * 16;
      gload16(A + (size_t)(row0 + rbase + srow) * HID + k0 + sseg * 8, As + rbase * 32);
    }
    gload16(W + (size_t)(col0 + wave * 16 + srow) * HID + k0 + sseg * 8, Bs + wave * 16 * 32);
    __syncthreads();

    short8 af[2], bfr[4];
    #pragma unroll
    for (int i = 0; i < 2; i++)
      af[i] = *reinterpret_cast<const short8*>(As + (wave * 32 + i * 16 + l16) * 32 + quad * 8);
    #pragma unroll
    for (int j = 0; j < 4; j++)
      bfr[j] = *reinterpret_cast<const short8*>(Bs + (j * 16 + l16) * 32 + quad * 8);
    #pragma unroll
    for (int i = 0; i < 2; i++)
      #pragma unroll
      for (int j = 0; j < 4; j++)
        acc[i][j] = __builtin_amdgcn_mfma_f32_16x16x32_bf16(af[i], bfr[j], acc[i][j], 0, 0, 0);
  }

  #pragma unroll
  for (int j = 0; j < 4; j++) {
    int n = col0 + j * 16 + l16;
    float bb = be[n];
    #pragma unroll
    for (int i = 0; i < 2; i++)
      #pragma unroll
      for (int rr = 0; rr < 4; rr++) {
        int s = row0 + wave * 32 + i * 16 + quad * 4 + rr;
        dst[(size_t)s * HID + n] = acc[i][j][rr] + bb;
      }
  }
}

// ---------------------------------------------------------------- attention (v18/v20, session best ~82us)
// Collapsed double softmax (w = 1+p): out = (Vsum + softmax1(S)V)/4097.
// v12 pipeline at 2 waves/SIMD — the empirical optimum of this decomposition:
//   v13/v14 (single-buffer + occupancy): slower; v17 (setprio): slower;
//   v19 (V-in-regs + 3 waves): spill catastrophe.
// 3-stage 2-deep register pipeline per tile t:
//   stage t+2 -> vmcnt(8) -> issue ds_read t+1 -> compute t (reg-only) -> lgkm(0)
// + biasfold rider as blockIdx.y==16.
struct AttnState {
  short8 qf[2][4];
  f32x16 Oa[2][2];
  f32x16 zacc;
  f32x2  zp[2];
};

__device__ __forceinline__ void loadregs(
    const unsigned short* kb, const unsigned short* vb,
    short8 (&kf)[4], short8 (&vf)[4])
{
  #pragma unroll
  for (int c = 0; c < 4; c++)
    kf[c] = *reinterpret_cast<const short8*>(kb + c * 512);
  #pragma unroll
  for (int w = 0; w < 4; w++)
    vf[w] = *reinterpret_cast<const short8*>(vb + w * 512);
}

__device__ __forceinline__ void attn_compute(
    const short8 (&kf)[4], const short8 (&vfr)[4], AttnState& st)
{
  #pragma unroll
  for (int qh = 0; qh < 2; qh++) {
    // S^T tile: 32 keys x 32 q (C: col=q=l32, row=key=(reg&3)+4hf+8(reg>>2))
    f32x16 acc = __builtin_amdgcn_mfma_f32_32x32x16_bf16(kf[0], st.qf[qh][0], st.zacc, 0, 0, 0);
    #pragma unroll
    for (int c = 1; c < 4; c++)
      acc = __builtin_amdgcn_mfma_f32_32x32x16_bf16(kf[c], st.qf[qh][c], acc, 0, 0, 0);

    // exp + pack: reg-octet [0..7] / [8..15] become K=16 A-operands directly
    unsigned int D[8];
    #pragma unroll
    for (int m = 0; m < 8; m++) {
      float t0 = __builtin_amdgcn_exp2f(acc[2 * m]);
      float t1 = __builtin_amdgcn_exp2f(acc[2 * m + 1]);
      f32x2 t = {t0, t1};
      st.zp[qh] += t;                      // v_pk_add_f32
      D[m] = pktrunc(t0, t1);
    }
    u32x4 dv0 = {D[0], D[1], D[2], D[3]};
    u32x4 dv1 = {D[4], D[5], D[6], D[7]};
    short8 A0 = __builtin_bit_cast(short8, dv0);
    short8 A1 = __builtin_bit_cast(short8, dv1);

    st.Oa[qh][0] = __builtin_amdgcn_mfma_f32_32x32x16_bf16(A0, vfr[0], st.Oa[qh][0], 0, 0, 0);
    st.Oa[qh][1] = __builtin_amdgcn_mfma_f32_32x32x16_bf16(A0, vfr[1], st.Oa[qh][1], 0, 0, 0);
    st.Oa[qh][0] = __builtin_amdgcn_mfma_f32_32x32x16_bf16(A1, vfr[2], st.Oa[qh][0], 0, 0, 0);
    st.Oa[qh][1] = __builtin_amdgcn_mfma_f32_32x32x16_bf16(A1, vfr[3], st.Oa[qh][1], 0, 0, 0);
  }
}

__device__ __forceinline__ void stage_tile(
    const unsigned short* gK, const unsigned short* gV,
    unsigned short* lK, unsigned short* lV)
{
  #pragma unroll
  for (int i = 0; i < 4; i++) gload16(gK + i * 512, lK + i * 512);
  #pragma unroll
  for (int i = 0; i < 4; i++) gload16(gV + i * 512, lV + i * 512);
}

__global__ __launch_bounds__(256, 2) void attn_kernel(
    const unsigned short* __restrict__ Q, const unsigned short* __restrict__ K2,
    const unsigned short* __restrict__ Vb, unsigned short* __restrict__ OUT,
    const float* __restrict__ Vsum, const float* __restrict__ wo,
    const float* __restrict__ bo, float* __restrict__ be)
{
  // ---- biasfold rider blocks (y == 16): be[n] = bo[n] + (Vsum.wo[n,:])/4097
  if (blockIdx.y == 16) {
    const int base = blockIdx.x * 16 + (threadIdx.x >> 6) * 4;
    const int l = threadIdx.x & 63;
    #pragma unroll
    for (int c = 0; c < 4; c++) {
      const int n = base + c;
      float acc = 0.f;
      #pragma unroll
      for (int i = 0; i < 16; i++)
        acc += Vsum[l + 64 * i] * wo[(size_t)n * HID + l + 64 * i];
      #pragma unroll
      for (int off = 32; off >= 1; off >>= 1) acc += __shfl_xor(acc, off);
      if (l == 0) be[n] = bo[n] + acc * (1.f / 4097.f);
    }
    return;
  }

  __shared__ unsigned short T[4][2][2][2048];   // [wave][dbuf][K|V][2048] = 64KB
  __shared__ float Zl[256];                      // [wave][64 q]
  float* Ored = reinterpret_cast<float*>(&T[0][0][0][0]);   // [4][64][64] after loop

  // XCD-aware remap: XCD x owns heads {2x,2x+1}: K2+Vb working set 2MB (L2-fit).
  const int lin = blockIdx.y * 64 + blockIdx.x;
  const int xcd = lin & 7, idx = lin >> 3;
  const int h = xcd * 2 + (idx >> 6);
  const int q0 = (idx & 63) * 64;

  const int tid = threadIdx.x;
  const int wave = tid >> 6, lane = tid & 63, hf = lane >> 5, l32 = lane & 31;

  AttnState st;
  // Q B-frags for BOTH q-halves (loop-invariant): B[k=c*16+hf*8+j][q=l32]
  #pragma unroll
  for (int qh = 0; qh < 2; qh++) {
    const unsigned short* qrow = Q + (size_t)(h * S + q0 + qh * 32 + l32) * DH;
    #pragma unroll
    for (int c = 0; c < 4; c++)
      st.qf[qh][c] = *reinterpret_cast<const short8*>(qrow + c * 16 + hf * 8);
  }
  #pragma unroll
  for (int r = 0; r < 16; r++) {
    st.zacc[r] = 0.f;
    st.Oa[0][0][r] = 0.f; st.Oa[0][1][r] = 0.f;
    st.Oa[1][0][r] = 0.f; st.Oa[1][1][r] = 0.f;
  }
  st.zp[0] = (f32x2){0.f, 0.f};
  st.zp[1] = (f32x2){0.f, 0.f};

  const unsigned short* Kb  = K2 + (size_t)h * 128 * 2048;
  const unsigned short* Vbb = Vb + (size_t)h * 128 * 2048;

  // wave handles tiles g = wave + 4*i, i = 0..31 (each tile = 4KB K + 4KB V)
  const unsigned short* gK = Kb  + (size_t)wave * 2048 + (size_t)lane * 8;
  const unsigned short* gV = Vbb + (size_t)wave * 2048 + (size_t)lane * 8;
  unsigned short* lK0 = &T[wave][0][0][0];   // wave-uniform LDS dests
  unsigned short* lV0 = &T[wave][0][1][0];
  unsigned short* lK1 = &T[wave][1][0][0];
  unsigned short* lV1 = &T[wave][1][1][0];
  const unsigned short* kb0 = &T[wave][0][0][0] + lane * 8;
  const unsigned short* vb0 = &T[wave][0][1][0] + lane * 8;
  const unsigned short* kb1 = &T[wave][1][0][0] + lane * 8;
  const unsigned short* vb1 = &T[wave][1][1][0] + lane * 8;
  const ptrdiff_t STR = 4 * 2048;   // 4 tiles ahead (wave stride)

  short8 kA[4], vA[4], kB[4], vB[4];

  // prologue: tile0 -> buf0 -> regsA; tile1 -> buf1 (in flight)
  stage_tile(gK, gV, lK0, lV0); gK += STR; gV += STR;   // out 8
  VMCNT0;
  loadregs(kb0, vb0, kA, vA);                           // ds_reads pending
  stage_tile(gK, gV, lK1, lV1); gK += STR; gV += STR;   // out 8 (buf1 untouched by reads)
  LGKM0;                                                // regsA valid; buf0 free for re-stage

  // 15 pairs: computes tiles 0..29, stages 2..31
  for (int p = 0; p < 15; p++) {
    // even t=2p: stage t+2->buf0, read t+1->B, compute A(t)
    stage_tile(gK, gV, lK0, lV0); gK += STR; gV += STR;   // out 16
    VMCNT8;                                               // t+1 landed
    loadregs(kb1, vb1, kB, vB);                           // pending
    attn_compute(kA, vA, st);                             // reg-only
    LGKM0;                                                // B valid; buf1 free
    // odd t=2p+1: stage t+3->buf1, read t+2->A, compute B(t+1)
    stage_tile(gK, gV, lK1, lV1); gK += STR; gV += STR;   // out 16
    VMCNT8;                                               // t+2 landed
    loadregs(kb0, vb0, kA, vA);                           // pending
    attn_compute(kB, vB, st);                             // reg-only
    LGKM0;                                                // A valid; buf0 free
  }
  // after loop: computed 0..29, A = tile30, outstanding = tile31 (8)
  VMCNT0;
  loadregs(kb1, vb1, kB, vB);    // tile31
  attn_compute(kA, vA, st);      // tile30
  attn_compute(kB, vB, st);      // tile31 (compiler inserts lgkm before use)

  // ---- epilogue: cross-wave reduction through the dead tile LDS ----
  __syncthreads();   // everyone done streaming; T reusable as Ored
  {
    float za = st.zp[0][0] + st.zp[0][1];
    float zb = st.zp[1][0] + st.zp[1][1];
    za += __shfl_xor(za, 32);
    zb += __shfl_xor(zb, 32);
    if (hf == 0) {
      Zl[wave * 64 + l32]      = za;
      Zl[wave * 64 + 32 + l32] = zb;
    }
    float* Ow = Ored + wave * 4096;   // [64 q][64 d]
    #pragma unroll
    for (int qh = 0; qh < 2; qh++)
      #pragma unroll
      for (int ng = 0; ng < 2; ng++)
        #pragma unroll
        for (int r = 0; r < 16; r++) {
          const int row = (r & 3) + 8 * (r >> 2) + 4 * hf;
          Ow[(qh * 32 + row) * 64 + ng * 32 + l32] = st.Oa[qh][ng][r];
        }
  }
  __syncthreads();
  {
    const int q = tid >> 2, d0 = (tid & 3) * 16;
    const float* O0 = Ored + q * 64 + d0;
    f32x4 s0 = *reinterpret_cast<const f32x4*>(O0);
    f32x4 s1 = *reinterpret_cast<const f32x4*>(O0 + 4);
    f32x4 s2 = *reinterpret_cast<const f32x4*>(O0 + 8);
    f32x4 s3 = *reinterpret_cast<const f32x4*>(O0 + 12);
    #pragma unroll
    for (int w = 1; w < 4; w++) {
      const float* Ow = Ored + w * 4096 + q * 64 + d0;
      s0 += *reinterpret_cast<const f32x4*>(Ow);
      s1 += *reinterpret_cast<const f32x4*>(Ow + 4);
      s2 += *reinterpret_cast<const f32x4*>(Ow + 8);
      s3 += *reinterpret_cast<const f32x4*>(Ow + 12);
    }
    const float zt = Zl[q] + Zl[64 + q] + Zl[128 + q] + Zl[192 + q];
    const float rz = 1.f / (zt * 4097.f);
    unsigned short* op = OUT + (size_t)(q0 + q) * HID + h * DH + d0;
    ushort4 u;
    u.x = f2bf(s0[0] * rz); u.y = f2bf(s0[1] * rz);
    u.z = f2bf(s0[2] * rz); u.w = f2bf(s0[3] * rz);
    *reinterpret_cast<ushort4*>(op) = u;
    u.x = f2bf(s1[0] * rz); u.y = f2bf(s1[1] * rz);
    u.z = f2bf(s1[2] * rz); u.w = f2bf(s1[3] * rz);
    *reinterpret_cast<ushort4*>(op + 4) = u;
    u.x = f2bf(s2[0] * rz); u.y = f2bf(s2[1] * rz);
    u.z = f2bf(s2[2] * rz); u.w = f2bf(s2[3] * rz);
    *reinterpret_cast<ushort4*>(op + 8) = u;
    u.x = f2bf(s3[0] * rz); u.y = f2bf(s3[1] * rz);
    u.z = f2bf(s3[2] * rz); u.w = f2bf(s3[3] * rz);
    *reinterpret_cast<ushort4*>(op + 12) = u;
  }
}

// ----------------------------------------------------------------
extern "C" void kernel_launch(void* const* d_in, const int* in_sizes, int n_in,
                              void* d_out, int out_size, void* d_ws, size_t ws_size,
                              hipStream_t stream) {
  const float* x  = (const float*)d_in[0];
  const float* wq = (const float*)d_in[1];
  const float* bq = (const float*)d_in[2];
  const float* wk = (const float*)d_in[3];
  const float* bk = (const float*)d_in[4];
  const float* wv = (const float*)d_in[5];
  const float* bv = (const float*)d_in[6];
  const float* wo = (const float*)d_in[7];
  const float* bo = (const float*)d_in[8];
  float* out = (float*)d_out;

  char* ws = (char*)d_ws;
  unsigned short* xb  = (unsigned short*)(ws);                 // 8 MB (reused for attn out)
  unsigned short* wqb = (unsigned short*)(ws + (8u  << 20));
  unsigned short* wkb = (unsigned short*)(ws + (10u << 20));
  unsigned short* wvb = (unsigned short*)(ws + (12u << 20));
  unsigned short* wob = (unsigned short*)(ws + (14u << 20));
  unsigned short* qw  = (unsigned short*)(ws + (16u << 20));   // [H][S][64] prescaled
  unsigned short* k2  = (unsigned short*)(ws + (24u << 20));   // frag-packed K (K=16 A-op)
  unsigned short* vb  = (unsigned short*)(ws + (32u << 20));   // frag-packed V (K=16 B-op, relabeled)
  float* vsum         = (float*)(ws + (40u << 20));            // [1024]
  float* be           = (float*)(ws + (40u << 20) + 65536);    // [1024]
  unsigned short* aw  = xb;

  cast_kernel<<<dim3(1024, 8), 256, 0, stream>>>(x, wq, wk, wv, wo, xb, wqb, wkb, wvb, wob, vsum);
  qkv_gemm_kernel<<<dim3(32, 8, 3), 256, 0, stream>>>(xb, wqb, wkb, wvb, bq, bk, bv, qw, k2, vb, vsum);
  attn_kernel<<<dim3(64, 17), 256, 0, stream>>>(qw, k2, vb, aw, vsum, wo, bo, be);
  out_gemm_kernel<<<dim3(32, 16), 256, 0, stream>>>(aw, wob, be, out);
}

// Round 18
// 227.665 us; speedup vs baseline: 1.6717x; 1.0071x over previous
//
#include <hip/hip_runtime.h>
#include <hip/hip_bf16.h>
#include <stdint.h>

#define S 4096
#define HID 1024
#define NH 16
#define DH 64

typedef __attribute__((ext_vector_type(8))) short short8;
typedef __attribute__((ext_vector_type(2))) float f32x2;
typedef __attribute__((ext_vector_type(4))) float f32x4;
typedef __attribute__((ext_vector_type(16))) float f32x16;
typedef __attribute__((ext_vector_type(4))) unsigned int u32x4;

#define VMCNT8 asm volatile("s_waitcnt vmcnt(8)" ::: "memory")
#define VMCNT0 asm volatile("s_waitcnt vmcnt(0)" ::: "memory")
#define LGKM0  asm volatile("s_waitcnt lgkmcnt(0)" ::: "memory")

__device__ __forceinline__ unsigned short f2bf(float f) {
  unsigned int u = __builtin_bit_cast(unsigned int, f);
  u += 0x7FFF + ((u >> 16) & 1);   // round-to-nearest-even
  return (unsigned short)(u >> 16);
}
// pack two fp32 -> bf16x2 dword by truncation (1 v_perm_b32)
__device__ __forceinline__ unsigned int pktrunc(float lo, float hi) {
  return __builtin_amdgcn_perm(__builtin_bit_cast(unsigned int, hi),
                               __builtin_bit_cast(unsigned int, lo), 0x07060302u);
}
// async global->LDS, 16B per lane. LDS pointer MUST be wave-uniform;
// HW writes lane i at ldsbase + i*16B (m104/m108 semantics).
__device__ __forceinline__ void gload16(const unsigned short* g, unsigned short* l) {
  __builtin_amdgcn_global_load_lds((const __attribute__((address_space(1))) unsigned int*)g,
                                   (__attribute__((address_space(3))) unsigned int*)l, 16, 0, 0);
}

// ---------------------------------------------------------------- cast fp32 -> bf16
// Right-sized grid (1024,8): y<4 -> x slices (4096 chunks), y>=4 -> one
// weight each (1024 chunks, exact). Block (0,4) zeroes vsum.
__global__ __launch_bounds__(256) void cast_kernel(
    const float* __restrict__ x,  const float* __restrict__ wq,
    const float* __restrict__ wk, const float* __restrict__ wv,
    const float* __restrict__ wo,
    unsigned short* __restrict__ xb,  unsigned short* __restrict__ wqb,
    unsigned short* __restrict__ wkb, unsigned short* __restrict__ wvb,
    unsigned short* __restrict__ wob, float* __restrict__ vsum)
{
  const int y = blockIdx.y, bx = blockIdx.x;
  const float* src; unsigned short* dst; int cx;
  if (y < 4)       { src = x;  dst = xb;  cx = y * 1024 + bx; }
  else if (y == 4) { src = wq; dst = wqb; cx = bx; }
  else if (y == 5) { src = wk; dst = wkb; cx = bx; }
  else if (y == 6) { src = wv; dst = wvb; cx = bx; }
  else             { src = wo; dst = wob; cx = bx; }
  if (y == 4 && bx == 0) {
    f32x4 z = {0.f, 0.f, 0.f, 0.f};
    reinterpret_cast<f32x4*>(vsum)[threadIdx.x] = z;   // 256*4 = 1024 floats
  }
  int i = (cx * 256 + threadIdx.x) * 4;
  float4 v = *reinterpret_cast<const float4*>(src + i);
  ushort4 o;
  o.x = f2bf(v.x); o.y = f2bf(v.y); o.z = f2bf(v.z); o.w = f2bf(v.w);
  *reinterpret_cast<ushort4*>(dst + i) = o;
}

// ---------------------------------------------------------------- 128x128 NT GEMM core (m97-style)
__device__ __forceinline__ void gemm128(
    const unsigned short* __restrict__ A, const unsigned short* __restrict__ W,
    unsigned short* As, unsigned short* Bs, f32x4 acc[4][4], int row0, int col0)
{
  const int tid = threadIdx.x;
  const int wave = tid >> 6, lane = tid & 63, quad = lane >> 4, l16 = lane & 15;
  const int wr = (wave >> 1) * 64, wc = (wave & 1) * 64;
  const int srow = lane >> 2, sseg = lane & 3;
  const f32x4 z = {0.f, 0.f, 0.f, 0.f};
  #pragma unroll
  for (int i = 0; i < 4; i++)
    #pragma unroll
    for (int j = 0; j < 4; j++) acc[i][j] = z;

  for (int k0 = 0; k0 < HID; k0 += 32) {
    __syncthreads();
    #pragma unroll
    for (int c = 0; c < 2; c++) {
      const int rbase = c * 64 + wave * 16;
      gload16(A + (size_t)(row0 + rbase + srow) * HID + k0 + sseg * 8, As + rbase * 32);
      gload16(W + (size_t)(col0 + rbase + srow) * HID + k0 + sseg * 8, Bs + rbase * 32);
    }
    __syncthreads();

    short8 af[4], bfr[4];
    #pragma unroll
    for (int i = 0; i < 4; i++)
      af[i] = *reinterpret_cast<const short8*>(As + (wr + i * 16 + l16) * 32 + quad * 8);
    #pragma unroll
    for (int j = 0; j < 4; j++)
      bfr[j] = *reinterpret_cast<const short8*>(Bs + (wc + j * 16 + l16) * 32 + quad * 8);
    #pragma unroll
    for (int i = 0; i < 4; i++)
      #pragma unroll
      for (int j = 0; j < 4; j++)
        acc[i][j] = __builtin_amdgcn_mfma_f32_16x16x32_bf16(af[i], bfr[j], acc[i][j], 0, 0, 0);
  }
}

// QKV projections. Q -> [H][S][64] prescaled by log2e/8.
// K -> K2 frag-packed (K=16 A-op): K2[(((h*128+g)*4+c)*64 + lane)*8 + j]
// V -> Vb frag-packed (K=16 B-op with keys bitswap23-relabeled).
// Epilogues route through a 32KB LDS image laid out exactly as the
// destination global bytes, then one barrier + coalesced dwordx4 copy-out.
// v22: Ep ALIASES As+Bs (dead after the GEMM loop) -> block LDS 48->32KB,
// 3 -> 4 blocks/CU (co-residency covers the 2-barrier loop's drain, same
// mechanism as v21's out_gemm retile win). One extra __syncthreads between
// the last fragment reads and the Ep overwrite.
__global__ __launch_bounds__(256) void qkv_gemm_kernel(
    const unsigned short* __restrict__ X,
    const unsigned short* __restrict__ Wq, const unsigned short* __restrict__ Wk,
    const unsigned short* __restrict__ Wv,
    const float* __restrict__ bq, const float* __restrict__ bk, const float* __restrict__ bv,
    unsigned short* __restrict__ Qo, unsigned short* __restrict__ K2o, unsigned short* __restrict__ Vbo,
    float* __restrict__ Vsum)
{
  __shared__ unsigned short U[16384];             // 32KB: [As 8KB | Bs 8KB] / Ep
  unsigned short* As = U;                         // 4096 shorts
  unsigned short* Bs = U + 4096;                  // 4096 shorts
  unsigned short* Ep = U;                         // 16384 shorts (after GEMM)
  const int zsel = blockIdx.z;
  const unsigned short* W = (zsel == 0) ? Wq : (zsel == 1) ? Wk : Wv;
  const float* bias        = (zsel == 0) ? bq : (zsel == 1) ? bk : bv;
  const int row0 = blockIdx.x * 128, col0 = blockIdx.y * 128;
  f32x4 acc[4][4];
  gemm128(X, W, As, Bs, acc, row0, col0);
  __syncthreads();   // all waves done reading As/Bs before Ep overwrites them

  const int tid = threadIdx.x;
  const int wave = tid >> 6, lane = tid & 63, quad = lane >> 4, l16 = lane & 15;
  const int wr = (wave >> 1) * 64, wc = (wave & 1) * 64;
  const int h0 = col0 >> 6, g0 = row0 >> 5;

  if (zsel == 0) {
    const float osc = 0.18033688011112042f;   // log2(e)/8
    #pragma unroll
    for (int j = 0; j < 4; j++) {
      int rc = wc + j * 16 + l16;             // 0..127 within tile
      float bb = bias[col0 + rc];
      int hh = rc >> 6, d = rc & 63;
      #pragma unroll
      for (int i = 0; i < 4; i++)
        #pragma unroll
        for (int rr = 0; rr < 4; rr++) {
          int srel = wr + i * 16 + quad * 4 + rr;
          Ep[hh * 8192 + srel * 64 + d] = f2bf((acc[i][j][rr] + bb) * osc);
        }
    }
  } else if (zsel == 1) {
    #pragma unroll
    for (int j = 0; j < 4; j++) {
      int rc = wc + j * 16 + l16;
      float bb = bias[col0 + rc];
      int hh = rc >> 6, dh = rc & 63;
      int c = dh >> 4, hfk = (dh >> 3) & 1, j8 = dh & 7;
      #pragma unroll
      for (int i = 0; i < 4; i++)
        #pragma unroll
        for (int rr = 0; rr < 4; rr++) {
          int srel = wr + i * 16 + quad * 4 + rr;
          int gl = srel >> 5, l32k = srel & 31;
          Ep[(hh * 4 + gl) * 2048 + (c * 64 + hfk * 32 + l32k) * 8 + j8] =
              f2bf(acc[i][j][rr] + bb);
        }
    }
  } else {
    // m = key&15 = quad*4+rr -> hf_v = quad&1, j = (quad>>1)*4 + rr, grp = i&1
    #pragma unroll
    for (int j = 0; j < 4; j++) {
      int rc = wc + j * 16 + l16;
      float bb = bias[col0 + rc];
      int hh = rc >> 6, dh = rc & 63;
      int ng = dh >> 5, l32v = dh & 31;
      int hf_v = quad & 1, jj0 = (quad >> 1) * 4;
      float colsum = 0.f;
      #pragma unroll
      for (int i = 0; i < 4; i++) {
        int gt4 = (wr + i * 16) >> 5;
        int grp = i & 1;
        float v0 = acc[i][j][0] + bb, v1 = acc[i][j][1] + bb;
        float v2 = acc[i][j][2] + bb, v3 = acc[i][j][3] + bb;
        colsum += (v0 + v1) + (v2 + v3);
        ushort4 pv;
        pv.x = f2bf(v0); pv.y = f2bf(v1); pv.z = f2bf(v2); pv.w = f2bf(v3);
        *reinterpret_cast<ushort4*>(
            Ep + (((hh * 4 + gt4) * 2 + grp) * 2 + ng) * 512 + (hf_v * 32 + l32v) * 8 + jj0) = pv;
      }
      // reduce 16-row partial across the 4 quads (same col), one atomic/col
      colsum += __shfl_xor(colsum, 16);
      colsum += __shfl_xor(colsum, 32);
      if (quad == 0) atomicAdd(&Vsum[col0 + rc], colsum);
    }
  }
  __syncthreads();

  // coalesced copy-out: 32KB in 8 rounds of 256 thr x 16B
  #pragma unroll
  for (int it = 0; it < 8; it++) {
    int flat = it * 2048 + tid * 8;           // short index, 16B-aligned
    u32x4 v = *reinterpret_cast<const u32x4*>(Ep + flat);
    if (zsel == 0) {
      int hh = flat >> 13;
      size_t goff = ((size_t)(h0 + hh) * S + row0) * 64 + (flat & 8191);
      *reinterpret_cast<u32x4*>(Qo + goff) = v;
    } else if (zsel == 1) {
      int sp = flat >> 11, hh = sp >> 2, g4 = sp & 3;
      size_t goff = (size_t)((h0 + hh) * 128 + g0 + g4) * 2048 + (flat & 2047);
      *reinterpret_cast<u32x4*>(K2o + goff) = v;
    } else {
      int sp = flat >> 9;
      int ng = sp & 1, grp = (sp >> 1) & 1, gt4 = (sp >> 2) & 3, hh = sp >> 4;
      size_t goff = (size_t)((((h0 + hh) * 128 + g0 + gt4) * 2 + grp) * 2 + ng) * 512 + (flat & 511);
      *reinterpret_cast<u32x4*>(Vbo + goff) = v;
    }
  }
}

// out = A @ W^T + bias_eff
// 128x64 tiles (grid 32x16 = 512 blocks = 2 blocks/CU): v21 win (+8us) —
// co-residency hides the per-k-step vmcnt(0)+barrier drain [m114].
__global__ __launch_bounds__(256) void out_gemm_kernel(
    const unsigned short* __restrict__ A, const unsigned short* __restrict__ W,
    const float* __restrict__ be, float* __restrict__ dst)
{
  __shared__ unsigned short As[128 * 32];   // 8KB
  __shared__ unsigned short Bs[64 * 32];    // 4KB
  const int row0 = blockIdx.x * 128, col0 = blockIdx.y * 64;
  const int tid = threadIdx.x;
  const int wave = tid >> 6, lane = tid & 63, quad = lane >> 4, l16 = lane & 15;
  const int srow = lane >> 2, sseg = lane & 3;
  f32x4 acc[2][4];
  const f32x4 z = {0.f, 0.f, 0.f, 0.f};
  #pragma unroll
  for (int i = 0; i < 2; i++)
    #pragma unroll
    for (int j = 0; j < 4; j++) acc[i][j] = z;

  for (int k0 = 0; k0 < HID; k0 += 32) {
    __syncthreads();
    #pragma unroll
    for (int c = 0; c < 2; c++) {
      const int rbase = c * 64 + wave * 16;
      gload16(A + (size_t)(row0 + rbase + srow) * HID + k0 + sseg * 8, As + rbase * 32);
    }
    gload16(W + (size_t)(col0 + wave * 16 + srow) * HID + k0 + sseg * 8, Bs + wave * 16 * 32);
    __syncthreads();

    short8 af[2], bfr[4];
    #pragma unroll
    for (int i = 0; i < 2; i++)
      af[i] = *reinterpret_cast<const short8*>(As + (wave * 32 + i * 16 + l16) * 32 + quad * 8);
    #pragma unroll
    for (int j = 0; j < 4; j++)
      bfr[j] = *reinterpret_cast<const short8*>(Bs + (j * 16 + l16) * 32 + quad * 8);
    #pragma unroll
    for (int i = 0; i < 2; i++)
      #pragma unroll
      for (int j = 0; j < 4; j++)
        acc[i][j] = __builtin_amdgcn_mfma_f32_16x16x32_bf16(af[i], bfr[j], acc[i][j], 0, 0, 0);
  }

  #pragma unroll
  for (int j = 0; j < 4; j++) {
    int n = col0 + j * 16 + l16;
    float bb = be[n];
    #pragma unroll
    for (int i = 0; i < 2; i++)
      #pragma unroll
      for (int rr = 0; rr < 4; rr++) {
        int s = row0 + wave * 32 + i * 16 + quad * 4 + rr;
        dst[(size_t)s * HID + n] = acc[i][j][rr] + bb;
      }
  }
}

// ---------------------------------------------------------------- attention (v18/v20, session best ~82us)
// Collapsed double softmax (w = 1+p): out = (Vsum + softmax1(S)V)/4097.
// v12 pipeline at 2 waves/SIMD — the empirical optimum of this decomposition:
//   v13/v14 (single-buffer + occupancy): slower; v17 (setprio): slower;
//   v19 (V-in-regs + 3 waves): spill catastrophe.
// 3-stage 2-deep register pipeline per tile t:
//   stage t+2 -> vmcnt(8) -> issue ds_read t+1 -> compute t (reg-only) -> lgkm(0)
// + biasfold rider as blockIdx.y==16.
struct AttnState {
  short8 qf[2][4];
  f32x16 Oa[2][2];
  f32x16 zacc;
  f32x2  zp[2];
};

__device__ __forceinline__ void loadregs(
    const unsigned short* kb, const unsigned short* vb,
    short8 (&kf)[4], short8 (&vf)[4])
{
  #pragma unroll
  for (int c = 0; c < 4; c++)
    kf[c] = *reinterpret_cast<const short8*>(kb + c * 512);
  #pragma unroll
  for (int w = 0; w < 4; w++)
    vf[w] = *reinterpret_cast<const short8*>(vb + w * 512);
}

__device__ __forceinline__ void attn_compute(
    const short8 (&kf)[4], const short8 (&vfr)[4], AttnState& st)
{
  #pragma unroll
  for (int qh = 0; qh < 2; qh++) {
    // S^T tile: 32 keys x 32 q (C: col=q=l32, row=key=(reg&3)+4hf+8(reg>>2))
    f32x16 acc = __builtin_amdgcn_mfma_f32_32x32x16_bf16(kf[0], st.qf[qh][0], st.zacc, 0, 0, 0);
    #pragma unroll
    for (int c = 1; c < 4; c++)
      acc = __builtin_amdgcn_mfma_f32_32x32x16_bf16(kf[c], st.qf[qh][c], acc, 0, 0, 0);

    // exp + pack: reg-octet [0..7] / [8..15] become K=16 A-operands directly
    unsigned int D[8];
    #pragma unroll
    for (int m = 0; m < 8; m++) {
      float t0 = __builtin_amdgcn_exp2f(acc[2 * m]);
      float t1 = __builtin_amdgcn_exp2f(acc[2 * m + 1]);
      f32x2 t = {t0, t1};
      st.zp[qh] += t;                      // v_pk_add_f32
      D[m] = pktrunc(t0, t1);
    }
    u32x4 dv0 = {D[0], D[1], D[2], D[3]};
    u32x4 dv1 = {D[4], D[5], D[6], D[7]};
    short8 A0 = __builtin_bit_cast(short8, dv0);
    short8 A1 = __builtin_bit_cast(short8, dv1);

    st.Oa[qh][0] = __builtin_amdgcn_mfma_f32_32x32x16_bf16(A0, vfr[0], st.Oa[qh][0], 0, 0, 0);
    st.Oa[qh][1] = __builtin_amdgcn_mfma_f32_32x32x16_bf16(A0, vfr[1], st.Oa[qh][1], 0, 0, 0);
    st.Oa[qh][0] = __builtin_amdgcn_mfma_f32_32x32x16_bf16(A1, vfr[2], st.Oa[qh][0], 0, 0, 0);
    st.Oa[qh][1] = __builtin_amdgcn_mfma_f32_32x32x16_bf16(A1, vfr[3], st.Oa[qh][1], 0, 0, 0);
  }
}

__device__ __forceinline__ void stage_tile(
    const unsigned short* gK, const unsigned short* gV,
    unsigned short* lK, unsigned short* lV)
{
  #pragma unroll
  for (int i = 0; i < 4; i++) gload16(gK + i * 512, lK + i * 512);
  #pragma unroll
  for (int i = 0; i < 4; i++) gload16(gV + i * 512, lV + i * 512);
}

__global__ __launch_bounds__(256, 2) void attn_kernel(
    const unsigned short* __restrict__ Q, const unsigned short* __restrict__ K2,
    const unsigned short* __restrict__ Vb, unsigned short* __restrict__ OUT,
    const float* __restrict__ Vsum, const float* __restrict__ wo,
    const float* __restrict__ bo, float* __restrict__ be)
{
  // ---- biasfold rider blocks (y == 16): be[n] = bo[n] + (Vsum.wo[n,:])/4097
  if (blockIdx.y == 16) {
    const int base = blockIdx.x * 16 + (threadIdx.x >> 6) * 4;
    const int l = threadIdx.x & 63;
    #pragma unroll
    for (int c = 0; c < 4; c++) {
      const int n = base + c;
      float acc = 0.f;
      #pragma unroll
      for (int i = 0; i < 16; i++)
        acc += Vsum[l + 64 * i] * wo[(size_t)n * HID + l + 64 * i];
      #pragma unroll
      for (int off = 32; off >= 1; off >>= 1) acc += __shfl_xor(acc, off);
      if (l == 0) be[n] = bo[n] + acc * (1.f / 4097.f);
    }
    return;
  }

  __shared__ unsigned short T[4][2][2][2048];   // [wave][dbuf][K|V][2048] = 64KB
  __shared__ float Zl[256];                      // [wave][64 q]
  float* Ored = reinterpret_cast<float*>(&T[0][0][0][0]);   // [4][64][64] after loop

  // XCD-aware remap: XCD x owns heads {2x,2x+1}: K2+Vb working set 2MB (L2-fit).
  const int lin = blockIdx.y * 64 + blockIdx.x;
  const int xcd = lin & 7, idx = lin >> 3;
  const int h = xcd * 2 + (idx >> 6);
  const int q0 = (idx & 63) * 64;

  const int tid = threadIdx.x;
  const int wave = tid >> 6, lane = tid & 63, hf = lane >> 5, l32 = lane & 31;

  AttnState st;
  // Q B-frags for BOTH q-halves (loop-invariant): B[k=c*16+hf*8+j][q=l32]
  #pragma unroll
  for (int qh = 0; qh < 2; qh++) {
    const unsigned short* qrow = Q + (size_t)(h * S + q0 + qh * 32 + l32) * DH;
    #pragma unroll
    for (int c = 0; c < 4; c++)
      st.qf[qh][c] = *reinterpret_cast<const short8*>(qrow + c * 16 + hf * 8);
  }
  #pragma unroll
  for (int r = 0; r < 16; r++) {
    st.zacc[r] = 0.f;
    st.Oa[0][0][r] = 0.f; st.Oa[0][1][r] = 0.f;
    st.Oa[1][0][r] = 0.f; st.Oa[1][1][r] = 0.f;
  }
  st.zp[0] = (f32x2){0.f, 0.f};
  st.zp[1] = (f32x2){0.f, 0.f};

  const unsigned short* Kb  = K2 + (size_t)h * 128 * 2048;
  const unsigned short* Vbb = Vb + (size_t)h * 128 * 2048;

  // wave handles tiles g = wave + 4*i, i = 0..31 (each tile = 4KB K + 4KB V)
  const unsigned short* gK = Kb  + (size_t)wave * 2048 + (size_t)lane * 8;
  const unsigned short* gV = Vbb + (size_t)wave * 2048 + (size_t)lane * 8;
  unsigned short* lK0 = &T[wave][0][0][0];   // wave-uniform LDS dests
  unsigned short* lV0 = &T[wave][0][1][0];
  unsigned short* lK1 = &T[wave][1][0][0];
  unsigned short* lV1 = &T[wave][1][1][0];
  const unsigned short* kb0 = &T[wave][0][0][0] + lane * 8;
  const unsigned short* vb0 = &T[wave][0][1][0] + lane * 8;
  const unsigned short* kb1 = &T[wave][1][0][0] + lane * 8;
  const unsigned short* vb1 = &T[wave][1][1][0] + lane * 8;
  const ptrdiff_t STR = 4 * 2048;   // 4 tiles ahead (wave stride)

  short8 kA[4], vA[4], kB[4], vB[4];

  // prologue: tile0 -> buf0 -> regsA; tile1 -> buf1 (in flight)
  stage_tile(gK, gV, lK0, lV0); gK += STR; gV += STR;   // out 8
  VMCNT0;
  loadregs(kb0, vb0, kA, vA);                           // ds_reads pending
  stage_tile(gK, gV, lK1, lV1); gK += STR; gV += STR;   // out 8 (buf1 untouched by reads)
  LGKM0;                                                // regsA valid; buf0 free for re-stage

  // 15 pairs: computes tiles 0..29, stages 2..31
  for (int p = 0; p < 15; p++) {
    // even t=2p: stage t+2->buf0, read t+1->B, compute A(t)
    stage_tile(gK, gV, lK0, lV0); gK += STR; gV += STR;   // out 16
    VMCNT8;                                               // t+1 landed
    loadregs(kb1, vb1, kB, vB);                           // pending
    attn_compute(kA, vA, st);                             // reg-only
    LGKM0;                                                // B valid; buf1 free
    // odd t=2p+1: stage t+3->buf1, read t+2->A, compute B(t+1)
    stage_tile(gK, gV, lK1, lV1); gK += STR; gV += STR;   // out 16
    VMCNT8;                                               // t+2 landed
    loadregs(kb0, vb0, kA, vA);                           // pending
    attn_compute(kB, vB, st);                             // reg-only
    LGKM0;                                                // A valid; buf0 free
  }
  // after loop: computed 0..29, A = tile30, outstanding = tile31 (8)
  VMCNT0;
  loadregs(kb1, vb1, kB, vB);    // tile31
  attn_compute(kA, vA, st);      // tile30
  attn_compute(kB, vB, st);      // tile31 (compiler inserts lgkm before use)

  // ---- epilogue: cross-wave reduction through the dead tile LDS ----
  __syncthreads();   // everyone done streaming; T reusable as Ored
  {
    float za = st.zp[0][0] + st.zp[0][1];
    float zb = st.zp[1][0] + st.zp[1][1];
    za += __shfl_xor(za, 32);
    zb += __shfl_xor(zb, 32);
    if (hf == 0) {
      Zl[wave * 64 + l32]      = za;
      Zl[wave * 64 + 32 + l32] = zb;
    }
    float* Ow = Ored + wave * 4096;   // [64 q][64 d]
    #pragma unroll
    for (int qh = 0; qh < 2; qh++)
      #pragma unroll
      for (int ng = 0; ng < 2; ng++)
        #pragma unroll
        for (int r = 0; r < 16; r++) {
          const int row = (r & 3) + 8 * (r >> 2) + 4 * hf;
          Ow[(qh * 32 + row) * 64 + ng * 32 + l32] = st.Oa[qh][ng][r];
        }
  }
  __syncthreads();
  {
    const int q = tid >> 2, d0 = (tid & 3) * 16;
    const float* O0 = Ored + q * 64 + d0;
    f32x4 s0 = *reinterpret_cast<const f32x4*>(O0);
    f32x4 s1 = *reinterpret_cast<const f32x4*>(O0 + 4);
    f32x4 s2 = *reinterpret_cast<const f32x4*>(O0 + 8);
    f32x4 s3 = *reinterpret_cast<const f32x4*>(O0 + 12);
    #pragma unroll
    for (int w = 1; w < 4; w++) {
      const float* Ow = Ored + w * 4096 + q * 64 + d0;
      s0 += *reinterpret_cast<const f32x4*>(Ow);
      s1 += *reinterpret_cast<const f32x4*>(Ow + 4);
      s2 += *reinterpret_cast<const f32x4*>(Ow + 8);
      s3 += *reinterpret_cast<const f32x4*>(Ow + 12);
    }
    const float zt = Zl[q] + Zl[64 + q] + Zl[128 + q] + Zl[192 + q];
    const float rz = 1.f / (zt * 4097.f);
    unsigned short* op = OUT + (size_t)(q0 + q) * HID + h * DH + d0;
    ushort4 u;
    u.x = f2bf(s0[0] * rz); u.y = f2bf(s0[1] * rz);
    u.z = f2bf(s0[2] * rz); u.w = f2bf(s0[3] * rz);
    *reinterpret_cast<ushort4*>(op) = u;
    u.x = f2bf(s1[0] * rz); u.y = f2bf(s1[1] * rz);
    u.z = f2bf(s1[2] * rz); u.w = f2bf(s1[3] * rz);
    *reinterpret_cast<ushort4*>(op + 4) = u;
    u.x = f2bf(s2[0] * rz); u.y = f2bf(s2[1] * rz);
    u.z = f2bf(s2[2] * rz); u.w = f2bf(s2[3] * rz);
    *reinterpret_cast<ushort4*>(op + 8) = u;
    u.x = f2bf(s3[0] * rz); u.y = f2bf(s3[1] * rz);
    u.z = f2bf(s3[2] * rz); u.w = f2bf(s3[3] * rz);
    *reinterpret_cast<ushort4*>(op + 12) = u;
  }
}

// ----------------------------------------------------------------
extern "C" void kernel_launch(void* const* d_in, const int* in_sizes, int n_in,
                              void* d_out, int out_size, void* d_ws, size_t ws_size,
                              hipStream_t stream) {
  const float* x  = (const float*)d_in[0];
  const float* wq = (const float*)d_in[1];
  const float* bq = (const float*)d_in[2];
  const float* wk = (const float*)d_in[3];
  const float* bk = (const float*)d_in[4];
  const float* wv = (const float*)d_in[5];
  const float* bv = (const float*)d_in[6];
  const float* wo = (const float*)d_in[7];
  const float* bo = (const float*)d_in[8];
  float* out = (float*)d_out;

  char* ws = (char*)d_ws;
  unsigned short* xb  = (unsigned short*)(ws);                 // 8 MB (reused for attn out)
  unsigned short* wqb = (unsigned short*)(ws + (8u  << 20));
  unsigned short* wkb = (unsigned short*)(ws + (10u << 20));
  unsigned short* wvb = (unsigned short*)(ws + (12u << 20));
  unsigned short* wob = (unsigned short*)(ws + (14u << 20));
  unsigned short* qw  = (unsigned short*)(ws + (16u << 20));   // [H][S][64] prescaled
  unsigned short* k2  = (unsigned short*)(ws + (24u << 20));   // frag-packed K (K=16 A-op)
  unsigned short* vb  = (unsigned short*)(ws + (32u << 20));   // frag-packed V (K=16 B-op, relabeled)
  float* vsum         = (float*)(ws + (40u << 20));            // [1024]
  float* be           = (float*)(ws + (40u << 20) + 65536);    // [1024]
  unsigned short* aw  = xb;

  cast_kernel<<<dim3(1024, 8), 256, 0, stream>>>(x, wq, wk, wv, wo, xb, wqb, wkb, wvb, wob, vsum);
  qkv_gemm_kernel<<<dim3(32, 8, 3), 256, 0, stream>>>(xb, wqb, wkb, wvb, bq, bk, bv, qw, k2, vb, vsum);
  attn_kernel<<<dim3(64, 17), 256, 0, stream>>>(qw, k2, vb, aw, vsum, wo, bo, be);
  out_gemm_kernel<<<dim3(32, 16), 256, 0, stream>>>(aw, wob, be, out);
}